// Round 7
// baseline (31579.538 us; speedup 1.0000x reference)
//
#include <hip/hip_runtime.h>
#include <stdint.h>
#include <math.h>

#define NB   16
#define HF   128
#define WF   128
#define NA   9
#define HW   (HF*WF)          // 16384
#define NTOT (HW*NA)          // 147456
#define PRE  12000
#define POST 2000
#define CAP  16384
#define NW   188              // 64-bit words for 12032 bits

// ws layout (bytes)
#define OFF_HIST  0u
#define SZ_HIST   (NB*65536u*4u)            // 4,194,304
#define OFF_META  (OFF_HIST + SZ_HIST)
#define SZ_META   4096u                     // [0..15] cutoff, [16..31] cand count, [32..47] nk
#define OFF_CAND  (OFF_META + SZ_META)
#define SZ_CAND   (NB*CAP*8u)               // 2,097,152
#define OFF_TB    (OFF_CAND + SZ_CAND)
#define SZ_TB     (5u*NB*PRE*4u)            // 3,840,000
#define OFF_KEEP  (OFF_TB + SZ_TB)
#define SZ_KEEP   (NB*POST*4u)              // 128,000

// base anchors = classic py-faster-rcnn table minus 1 (base [0,0,15,15]).
// Verified against published generate_anchors output. (Bug history: a8.y2
// was 351 in rounds 0-4; correct value is 359.)
__constant__ float c_ax1[NA] = {-84.f,-176.f,-360.f,-56.f,-120.f,-248.f,-36.f,-80.f,-168.f};
__constant__ float c_ay1[NA] = {-40.f,-88.f,-184.f,-56.f,-120.f,-248.f,-80.f,-168.f,-344.f};
__constant__ float c_ax2[NA] = { 99.f, 191.f, 375.f, 71.f, 135.f, 263.f, 51.f, 95.f, 183.f};
__constant__ float c_ay2[NA] = { 55.f, 103.f, 199.f, 71.f, 135.f, 263.f, 95.f, 183.f, 359.f};

__device__ __forceinline__ uint32_t score_key(float f){
  uint32_t b = __float_as_uint(f);
  uint32_t u = (b & 0x80000000u) ? ~b : (b | 0x80000000u);
  return ~u;   // ascending key = descending score; idx in low bits -> stable ties
}

// exact reference IoU test, no FMA contraction
__device__ __forceinline__ bool iou_gt(float ax1,float ay1,float ax2,float ay2,float aa,
                                       float bx1,float by1,float bx2,float by2,float ba){
  float xx1 = fmaxf(ax1,bx1);
  float yy1 = fmaxf(ay1,by1);
  float xx2 = fminf(ax2,bx2);
  float yy2 = fminf(ay2,by2);
  float w = fmaxf(__fadd_rn(__fsub_rn(xx2,xx1),1.0f), 0.0f);
  float h = fmaxf(__fadd_rn(__fsub_rn(yy2,yy1),1.0f), 0.0f);
  float inter = __fmul_rn(w,h);
  float denom = __fsub_rn(__fadd_rn(aa,ba), inter);
  float iou   = __fdiv_rn(inter, denom);
  return iou > 0.7f;
}

// -------- pass 1: histogram of score keys (top 16 bits) --------
__global__ void prep_k(const float* __restrict__ scores, uint32_t* __restrict__ hist){
  int g = blockIdx.x*256 + threadIdx.x;
  if (g >= NB*NTOT) return;
  int hw = g & (HW-1);
  int t  = g >> 14;
  int ch = t % NA;
  int b  = t / NA;
  float s = scores[((size_t)(b*2*NA + NA + ch) << 14) + hw];
  uint32_t k = score_key(s);
  atomicAdd(&hist[((uint32_t)b<<16) + (k>>16)], 1u);
}

// -------- pass 2: find cutoff bucket per batch --------
__global__ __launch_bounds__(1024) void scanhist_k(const uint32_t* __restrict__ hist,
                                                   uint32_t* __restrict__ meta){
  int b = blockIdx.x, t = threadIdx.x;
  const uint32_t* hh = hist + ((uint32_t)b<<16);
  int base = t<<6;
  uint32_t s=0;
  for (int i=0;i<64;i++) s += hh[base+i];
  __shared__ uint32_t part[1024];
  part[t]=s; __syncthreads();
  for (int off=1; off<1024; off<<=1){
    uint32_t v = (t>=off)? part[t-off] : 0u;
    __syncthreads();
    part[t] += v;
    __syncthreads();
  }
  uint32_t incl = part[t], excl = incl - s;
  if (excl < PRE && incl >= PRE){
    uint32_t run = excl;
    for (int i=0;i<64;i++){
      run += hh[base+i];
      if (run >= PRE){ meta[b] = (uint32_t)(base+i); break; }
    }
  }
}

// -------- pass 3: gather candidates with bucket <= cutoff --------
__global__ void gather_k(const float* __restrict__ scores, uint32_t* __restrict__ meta,
                         uint64_t* __restrict__ cand){
  int g = blockIdx.x*256 + threadIdx.x;
  if (g >= NB*NTOT) return;
  int hw = g & (HW-1);
  int t  = g >> 14;
  int ch = t % NA;
  int b  = t / NA;
  float s = scores[((size_t)(b*2*NA + NA + ch) << 14) + hw];
  uint32_t k = score_key(s);
  if ((k>>16) <= meta[b]){
    uint32_t pos = atomicAdd(&meta[16+b], 1u);
    if (pos < CAP){
      uint32_t idx = (uint32_t)hw*NA + (uint32_t)ch;
      cand[((size_t)b<<14) + pos] = ((uint64_t)k << 18) | (uint64_t)idx;
    }
  }
}

// -------- pass 4: per-batch bitonic sort of 16384 keys --------
__global__ __launch_bounds__(1024) void bsort_k(uint64_t* __restrict__ buf){
  uint64_t* A_ = buf + ((size_t)blockIdx.x << 14);
  int t = threadIdx.x;
  for (unsigned k = 2; k <= 16384u; k <<= 1){
    for (unsigned j = k >> 1; j > 0; j >>= 1){
      for (int i = t; i < 16384; i += 1024){
        int l = i ^ (int)j;
        if (l > i){
          uint64_t a = A_[i], b = A_[l];
          bool asc = ((i & (int)k) == 0);
          bool swap = asc ? (a > b) : (a < b);
          if (swap){ A_[i] = b; A_[l] = a; }
        }
      }
      __syncthreads();
    }
  }
}

// -------- pass 5: decode top-12000 boxes (exact f32 ref arithmetic) --------
__global__ void extract_k(const uint64_t* __restrict__ cand2,
                          const float* __restrict__ deltas,
                          const float* __restrict__ iminfo,
                          float* __restrict__ tb){
  int g = blockIdx.x*256 + threadIdx.x;
  if (g >= NB*PRE) return;
  int b = g / PRE, j = g - b*PRE;
  uint64_t K = cand2[((size_t)b<<14) + j];
  uint32_t idx = (uint32_t)K & 0x3FFFFu;
  int ch = (int)(idx % NA);
  int hw = (int)(idx / NA);
  int w  = hw & (WF-1);
  int h  = hw >> 7;
  float sx = (float)(w*16), sy = (float)(h*16);
  float ax1 = c_ax1[ch]+sx, ay1 = c_ay1[ch]+sy, ax2 = c_ax2[ch]+sx, ay2 = c_ay2[ch]+sy;
  const float* dp = deltas + ((size_t)(b*4*NA + ch*4) << 14) + hw;
  float dx = dp[0], dy = dp[HW], dwv = dp[2*HW], dhv = dp[3*HW];
  float aw  = __fadd_rn(__fsub_rn(ax2,ax1),1.f);
  float ah  = __fadd_rn(__fsub_rn(ay2,ay1),1.f);
  float acx = __fadd_rn(ax1, __fmul_rn(0.5f,aw));
  float acy = __fadd_rn(ay1, __fmul_rn(0.5f,ah));
  float pcx = __fadd_rn(__fmul_rn(dx,aw), acx);
  float pcy = __fadd_rn(__fmul_rn(dy,ah), acy);
  float ew  = (float)exp((double)dwv);
  float eh  = (float)exp((double)dhv);
  float pw  = __fmul_rn(ew, aw);
  float ph  = __fmul_rn(eh, ah);
  float hx  = __fmul_rn(0.5f,pw), hy = __fmul_rn(0.5f,ph);
  float x1 = __fsub_rn(pcx,hx), y1 = __fsub_rn(pcy,hy);
  float x2 = __fadd_rn(pcx,hx), y2 = __fadd_rn(pcy,hy);
  float maxx = __fsub_rn(iminfo[b*3+1],1.f);
  float maxy = __fsub_rn(iminfo[b*3+0],1.f);
  x1 = fminf(fmaxf(x1,0.f),maxx); y1 = fminf(fmaxf(y1,0.f),maxy);
  x2 = fminf(fmaxf(x2,0.f),maxx); y2 = fminf(fmaxf(y2,0.f),maxy);
  float area = __fmul_rn(__fadd_rn(__fsub_rn(x2,x1),1.f), __fadd_rn(__fsub_rn(y2,y1),1.f));
  int o = b*PRE + j;
  tb[o]            = x1;
  tb[NB*PRE + o]   = y1;
  tb[2*NB*PRE + o] = x2;
  tb[3*NB*PRE + o] = y2;
  tb[4*NB*PRE + o] = area;
}

// -------- serial greedy NMS: literal transcription of the reference --------
__global__ __launch_bounds__(1024) void nms_serial_k(const float* __restrict__ tb,
                                                     uint32_t* __restrict__ keep,
                                                     uint32_t* __restrict__ meta){
  const int b = blockIdx.x;
  const int t = threadIdx.x;
  __shared__ uint64_t sup[NW];
  __shared__ float bx[5];
  __shared__ int s_idx;
  __shared__ int red[16];
  for (int i=t; i<NW; i+=1024) sup[i] = 0;
  __syncthreads();
  if (t==0) sup[NW-1] = ~((1ULL<<32)-1ULL);   // j in [12000,12032) pre-suppressed
  __syncthreads();
  const float* P = tb + b*PRE;
  int nk = 0;
  for (int step=0; step<POST; step++){
    int c = 0x7FFFFFFF;
    if (t < NW){
      uint64_t w = ~sup[t];
      if (w) c = (t<<6) + (__ffsll((unsigned long long)w) - 1);
    }
    for (int off=32; off; off>>=1){
      int o = __shfl_down(c, off);
      c = min(c, o);
    }
    if ((t&63)==0) red[t>>6] = c;
    __syncthreads();
    if (t==0){
      int m = red[0];
      #pragma unroll
      for (int q=1;q<16;q++) m = min(m, red[q]);
      s_idx = m;
    }
    __syncthreads();
    int idx = s_idx;
    if (idx >= PRE) break;
    nk = step+1;
    if (t < 5)  bx[t] = P[t*(NB*PRE) + idx];
    if (t == 0) keep[b*POST + step] = (uint32_t)idx;
    __syncthreads();
    float kx1=bx[0],ky1=bx[1],kx2=bx[2],ky2=bx[3],ka=bx[4];
    int j0 = t*12;
    uint64_t m0=0, m1=0;
    int w0 = j0>>6;
    for (int q=0; q<12; q++){
      int j = j0+q;
      if (j >= PRE) break;
      bool s = iou_gt(kx1,ky1,kx2,ky2,ka,
                      P[j], P[NB*PRE+j], P[2*NB*PRE+j], P[3*NB*PRE+j], P[4*NB*PRE+j]);
      if (s){
        int w = j>>6;
        uint64_t bit = 1ULL << (j&63);
        if (w==w0) m0 |= bit; else m1 |= bit;
      }
    }
    if (m0) atomicOr((unsigned long long*)&sup[w0],   (unsigned long long)m0);
    if (m1) atomicOr((unsigned long long*)&sup[w0+1], (unsigned long long)m1);
    __syncthreads();
  }
  if (t==0) meta[32+b] = (uint32_t)nk;
}

// -------- output (f32) --------
__global__ void finalize_k(const float* __restrict__ tb, const uint32_t* __restrict__ keep,
                           const uint32_t* __restrict__ meta, float* __restrict__ out){
  int g = blockIdx.x*256 + threadIdx.x;
  if (g >= NB*POST) return;
  int b = g / POST, i = g - b*POST;
  float x1=0.f,y1=0.f,x2=0.f,y2=0.f;
  if (i < (int)meta[32+b]){
    int j = (int)keep[b*POST+i];
    int o = b*PRE + j;
    x1=tb[o]; y1=tb[NB*PRE+o]; x2=tb[2*NB*PRE+o]; y2=tb[3*NB*PRE+o];
  }
  float* op = out + (size_t)g*5;
  op[0]=(float)b; op[1]=x1; op[2]=y1; op[3]=x2; op[4]=y2;
}

extern "C" void kernel_launch(void* const* d_in, const int* in_sizes, int n_in,
                              void* d_out, int out_size, void* d_ws, size_t ws_size,
                              hipStream_t stream){
  (void)in_sizes; (void)n_in; (void)out_size; (void)ws_size;
  const float* scores = (const float*)d_in[0];
  const float* deltas = (const float*)d_in[1];
  const float* iminfo = (const float*)d_in[2];
  float* out = (float*)d_out;
  char* ws = (char*)d_ws;

  uint32_t* hist  = (uint32_t*)(ws + OFF_HIST);
  uint32_t* meta  = (uint32_t*)(ws + OFF_META);
  uint64_t* cand  = (uint64_t*)(ws + OFF_CAND);
  float*    tb    = (float*)   (ws + OFF_TB);
  uint32_t* keep  = (uint32_t*)(ws + OFF_KEEP);

  hipMemsetAsync(ws + OFF_HIST, 0, SZ_HIST + SZ_META, stream);
  hipMemsetAsync(ws + OFF_CAND, 0xFF, SZ_CAND, stream);

  prep_k      <<<(NB*NTOT+255)/256, 256, 0, stream>>>(scores, hist);
  scanhist_k  <<<NB, 1024, 0, stream>>>(hist, meta);
  gather_k    <<<(NB*NTOT+255)/256, 256, 0, stream>>>(scores, meta, cand);
  bsort_k     <<<NB, 1024, 0, stream>>>(cand);
  extract_k   <<<(NB*PRE+255)/256, 256, 0, stream>>>(cand, deltas, iminfo, tb);
  nms_serial_k<<<NB, 1024, 0, stream>>>(tb, keep, meta);
  finalize_k  <<<(NB*POST+255)/256, 256, 0, stream>>>(tb, keep, meta, out);
}

// Round 8
// 7944.031 us; speedup vs baseline: 3.9753x; 3.9753x over previous
//
#include <hip/hip_runtime.h>
#include <stdint.h>
#include <math.h>

#define NB   16
#define HF   128
#define WF   128
#define NA   9
#define HW   (HF*WF)          // 16384
#define NTOT (HW*NA)          // 147456
#define PRE  12000
#define POST 2000
#define CAP  16384
#define CHUNK 2048
#define NPH  6

// ws layout (bytes)
#define OFF_HIST  0u
#define SZ_HIST   (NB*65536u*4u)            // 4,194,304
#define OFF_META  (OFF_HIST + SZ_HIST)
#define SZ_META   4096u                     // [0..15] cutoff, [16..31] cand count, [32..47] nk
#define OFF_CAND  (OFF_META + SZ_META)
#define SZ_CAND   (NB*CAP*8u)               // 2,097,152
#define OFF_TB    (OFF_CAND + SZ_CAND)
#define SZ_TB     (5u*NB*PRE*4u)            // 3,840,000
#define OFF_KEEP  (OFF_TB + SZ_TB)
#define SZ_KEEP   (NB*POST*4u)              // 128,000
#define OFF_PRES  (OFF_KEEP + SZ_KEEP)
#define SZ_PRES   (NB*32u*8u)               // 4,096
#define OFF_M     (OFF_PRES + SZ_PRES)
#define SZ_M      ((size_t)NB*CHUNK*32u*8u) // 8,388,608  (total ~18.7 MB)

// base anchors = classic py-faster-rcnn table minus 1 (base [0,0,15,15]); a8.y2=359.
__constant__ float c_ax1[NA] = {-84.f,-176.f,-360.f,-56.f,-120.f,-248.f,-36.f,-80.f,-168.f};
__constant__ float c_ay1[NA] = {-40.f,-88.f,-184.f,-56.f,-120.f,-248.f,-80.f,-168.f,-344.f};
__constant__ float c_ax2[NA] = { 99.f, 191.f, 375.f, 71.f, 135.f, 263.f, 51.f, 95.f, 183.f};
__constant__ float c_ay2[NA] = { 55.f, 103.f, 199.f, 71.f, 135.f, 263.f, 95.f, 183.f, 359.f};

__device__ __forceinline__ uint32_t score_key(float f){
  uint32_t b = __float_as_uint(f);
  uint32_t u = (b & 0x80000000u) ? ~b : (b | 0x80000000u);
  return ~u;   // ascending key = descending score; idx in low bits -> stable ties
}

// exact reference IoU test, no FMA contraction
__device__ __forceinline__ bool iou_gt(float ax1,float ay1,float ax2,float ay2,float aa,
                                       float bx1,float by1,float bx2,float by2,float ba){
  float xx1 = fmaxf(ax1,bx1);
  float yy1 = fmaxf(ay1,by1);
  float xx2 = fminf(ax2,bx2);
  float yy2 = fminf(ay2,by2);
  float w = fmaxf(__fadd_rn(__fsub_rn(xx2,xx1),1.0f), 0.0f);
  float h = fmaxf(__fadd_rn(__fsub_rn(yy2,yy1),1.0f), 0.0f);
  float inter = __fmul_rn(w,h);
  float denom = __fsub_rn(__fadd_rn(aa,ba), inter);
  float iou   = __fdiv_rn(inter, denom);
  return iou > 0.7f;
}

// -------- pass 1: histogram of score keys (top 16 bits) --------
__global__ void prep_k(const float* __restrict__ scores, uint32_t* __restrict__ hist){
  int g = blockIdx.x*256 + threadIdx.x;
  if (g >= NB*NTOT) return;
  int hw = g & (HW-1);
  int t  = g >> 14;
  int ch = t % NA;
  int b  = t / NA;
  float s = scores[((size_t)(b*2*NA + NA + ch) << 14) + hw];
  uint32_t k = score_key(s);
  atomicAdd(&hist[((uint32_t)b<<16) + (k>>16)], 1u);
}

// -------- pass 2: find cutoff bucket per batch --------
__global__ __launch_bounds__(1024) void scanhist_k(const uint32_t* __restrict__ hist,
                                                   uint32_t* __restrict__ meta){
  int b = blockIdx.x, t = threadIdx.x;
  const uint32_t* hh = hist + ((uint32_t)b<<16);
  int base = t<<6;
  uint32_t s=0;
  for (int i=0;i<64;i++) s += hh[base+i];
  __shared__ uint32_t part[1024];
  part[t]=s; __syncthreads();
  for (int off=1; off<1024; off<<=1){
    uint32_t v = (t>=off)? part[t-off] : 0u;
    __syncthreads();
    part[t] += v;
    __syncthreads();
  }
  uint32_t incl = part[t], excl = incl - s;
  if (excl < PRE && incl >= PRE){
    uint32_t run = excl;
    for (int i=0;i<64;i++){
      run += hh[base+i];
      if (run >= PRE){ meta[b] = (uint32_t)(base+i); break; }
    }
  }
}

// -------- pass 3: gather candidates with bucket <= cutoff --------
__global__ void gather_k(const float* __restrict__ scores, uint32_t* __restrict__ meta,
                         uint64_t* __restrict__ cand){
  int g = blockIdx.x*256 + threadIdx.x;
  if (g >= NB*NTOT) return;
  int hw = g & (HW-1);
  int t  = g >> 14;
  int ch = t % NA;
  int b  = t / NA;
  float s = scores[((size_t)(b*2*NA + NA + ch) << 14) + hw];
  uint32_t k = score_key(s);
  if ((k>>16) <= meta[b]){
    uint32_t pos = atomicAdd(&meta[16+b], 1u);
    if (pos < CAP){
      uint32_t idx = (uint32_t)hw*NA + (uint32_t)ch;
      cand[((size_t)b<<14) + pos] = ((uint64_t)k << 18) | (uint64_t)idx;
    }
  }
}

// -------- pass 4: per-batch bitonic sort of 16384 keys --------
__global__ __launch_bounds__(1024) void bsort_k(uint64_t* __restrict__ buf){
  uint64_t* A_ = buf + ((size_t)blockIdx.x << 14);
  int t = threadIdx.x;
  for (unsigned k = 2; k <= 16384u; k <<= 1){
    for (unsigned j = k >> 1; j > 0; j >>= 1){
      for (int i = t; i < 16384; i += 1024){
        int l = i ^ (int)j;
        if (l > i){
          uint64_t a = A_[i], b = A_[l];
          bool asc = ((i & (int)k) == 0);
          bool swap = asc ? (a > b) : (a < b);
          if (swap){ A_[i] = b; A_[l] = a; }
        }
      }
      __syncthreads();
    }
  }
}

// -------- pass 5: decode top-12000 boxes (exact f32 ref arithmetic) --------
__global__ void extract_k(const uint64_t* __restrict__ cand2,
                          const float* __restrict__ deltas,
                          const float* __restrict__ iminfo,
                          float* __restrict__ tb){
  int g = blockIdx.x*256 + threadIdx.x;
  if (g >= NB*PRE) return;
  int b = g / PRE, j = g - b*PRE;
  uint64_t K = cand2[((size_t)b<<14) + j];
  uint32_t idx = (uint32_t)K & 0x3FFFFu;
  int ch = (int)(idx % NA);
  int hw = (int)(idx / NA);
  int w  = hw & (WF-1);
  int h  = hw >> 7;
  float sx = (float)(w*16), sy = (float)(h*16);
  float ax1 = c_ax1[ch]+sx, ay1 = c_ay1[ch]+sy, ax2 = c_ax2[ch]+sx, ay2 = c_ay2[ch]+sy;
  const float* dp = deltas + ((size_t)(b*4*NA + ch*4) << 14) + hw;
  float dx = dp[0], dy = dp[HW], dwv = dp[2*HW], dhv = dp[3*HW];
  float aw  = __fadd_rn(__fsub_rn(ax2,ax1),1.f);
  float ah  = __fadd_rn(__fsub_rn(ay2,ay1),1.f);
  float acx = __fadd_rn(ax1, __fmul_rn(0.5f,aw));
  float acy = __fadd_rn(ay1, __fmul_rn(0.5f,ah));
  float pcx = __fadd_rn(__fmul_rn(dx,aw), acx);
  float pcy = __fadd_rn(__fmul_rn(dy,ah), acy);
  float ew  = (float)exp((double)dwv);
  float eh  = (float)exp((double)dhv);
  float pw  = __fmul_rn(ew, aw);
  float ph  = __fmul_rn(eh, ah);
  float hx  = __fmul_rn(0.5f,pw), hy = __fmul_rn(0.5f,ph);
  float x1 = __fsub_rn(pcx,hx), y1 = __fsub_rn(pcy,hy);
  float x2 = __fadd_rn(pcx,hx), y2 = __fadd_rn(pcy,hy);
  float maxx = __fsub_rn(iminfo[b*3+1],1.f);
  float maxy = __fsub_rn(iminfo[b*3+0],1.f);
  x1 = fminf(fmaxf(x1,0.f),maxx); y1 = fminf(fmaxf(y1,0.f),maxy);
  x2 = fminf(fmaxf(x2,0.f),maxx); y2 = fminf(fmaxf(y2,0.f),maxy);
  float area = __fmul_rn(__fadd_rn(__fsub_rn(x2,x1),1.f), __fadd_rn(__fsub_rn(y2,y1),1.f));
  int o = b*PRE + j;
  tb[o]            = x1;
  tb[NB*PRE + o]   = y1;
  tb[2*NB*PRE + o] = x2;
  tb[3*NB*PRE + o] = y2;
  tb[4*NB*PRE + o] = area;
}

// -------- NMS phase a: chunk candidates vs already-kept boxes --------
__global__ void cross_k(const float* __restrict__ tb, const uint32_t* __restrict__ keep,
                        const uint32_t* __restrict__ meta, uint64_t* __restrict__ presup,
                        int base){
  int b  = blockIdx.y;
  int jl = blockIdx.x*256 + threadIdx.x;
  int j  = base + jl;
  bool valid = (j < PRE);
  float x1=0,y1=0,x2=0,y2=0,ar=0;
  if (valid){
    int o = b*PRE + j;
    x1=tb[o]; y1=tb[NB*PRE+o]; x2=tb[2*NB*PRE+o]; y2=tb[3*NB*PRE+o]; ar=tb[4*NB*PRE+o];
  }
  int nk = (int)meta[32+b];
  __shared__ float kx1[256],ky1[256],kx2[256],ky2[256],kar[256];
  bool supp = !valid;
  for (int k0=0; k0<nk; k0+=256){
    int kk = k0 + threadIdx.x;
    if (kk < nk){
      int kj = (int)keep[b*POST+kk];
      int o = b*PRE + kj;
      kx1[threadIdx.x]=tb[o]; ky1[threadIdx.x]=tb[NB*PRE+o];
      kx2[threadIdx.x]=tb[2*NB*PRE+o]; ky2[threadIdx.x]=tb[3*NB*PRE+o];
      kar[threadIdx.x]=tb[4*NB*PRE+o];
    }
    __syncthreads();
    int lim = min(256, nk-k0);
    if (!supp){
      for (int q=0;q<lim;q++){
        if (iou_gt(kx1[q],ky1[q],kx2[q],ky2[q],kar[q], x1,y1,x2,y2,ar)){ supp=true; break; }
      }
    }
    __syncthreads();
  }
  unsigned long long m = __ballot(supp);
  if ((threadIdx.x & 63)==0) presup[b*32 + (jl>>6)] = m;
}

// -------- NMS phase b: intra-chunk pairwise bit-matrix --------
__global__ void intra_k(const float* __restrict__ tb, uint64_t* __restrict__ Mm, int base){
  int b  = blockIdx.y;
  int il = blockIdx.x*8 + (threadIdx.x>>5);
  int jw = threadIdx.x & 31;
  __shared__ float sx1[CHUNK],sy1[CHUNK],sx2[CHUNK],sy2[CHUNK],sar[CHUNK]; // 40 KB
  for (int s = threadIdx.x; s < CHUNK; s += 256){
    int j = base + s;
    if (j < PRE){
      int o = b*PRE + j;
      sx1[s]=tb[o]; sy1[s]=tb[NB*PRE+o]; sx2[s]=tb[2*NB*PRE+o]; sy2[s]=tb[3*NB*PRE+o]; sar[s]=tb[4*NB*PRE+o];
    } else { sx1[s]=0.f; sy1[s]=0.f; sx2[s]=-10.f; sy2[s]=-10.f; sar[s]=1.f; }
  }
  __syncthreads();
  size_t mo = (((size_t)b*CHUNK) + (size_t)il)*32 + jw;
  int i = base + il;
  if (i >= PRE)          { Mm[mo] = 0; return; }
  if ((jw+1)*64 <= il)   { Mm[mo] = 0; return; }   // fully below diagonal
  float x1=sx1[il], y1=sy1[il], x2=sx2[il], y2=sy2[il], ar=sar[il];
  uint64_t bits = 0;
  int jbase = jw*64;
  for (int q=0;q<64;q++){
    int jl = jbase+q;
    bool s = (base+jl < PRE) && iou_gt(x1,y1,x2,y2,ar, sx1[jl],sy1[jl],sx2[jl],sy2[jl],sar[jl]);
    bits |= ((uint64_t)s) << q;
  }
  Mm[mo] = bits;
}

// -------- NMS phase c: bit-serial greedy scan (1 wave per batch) --------
__global__ __launch_bounds__(64) void scan_k(const uint64_t* __restrict__ Mm,
                                             const uint64_t* __restrict__ presup,
                                             uint32_t* __restrict__ keep,
                                             uint32_t* __restrict__ meta,
                                             int base){
  int b = blockIdx.x;
  int l = threadIdx.x;
  uint64_t acc = (l<32) ? presup[b*32+l] : ~0ULL;
  int nk = (int)meta[32+b];
  const uint64_t* Mb = Mm + (size_t)b*CHUNK*32;
  for (int jl=0; jl<CHUNK; jl++){
    if (nk >= POST) break;
    uint64_t wv = __shfl(acc, jl>>6);
    if (!((wv >> (jl&63)) & 1ULL)){
      if (l==0) keep[b*POST+nk] = (uint32_t)(base + jl);
      nk++;
      if (l<32) acc |= Mb[(size_t)jl*32 + l];   // row OR (diag bit = self)
    }
  }
  if (l==0) meta[32+b] = (uint32_t)nk;
}

// -------- output (f32) --------
__global__ void finalize_k(const float* __restrict__ tb, const uint32_t* __restrict__ keep,
                           const uint32_t* __restrict__ meta, float* __restrict__ out){
  int g = blockIdx.x*256 + threadIdx.x;
  if (g >= NB*POST) return;
  int b = g / POST, i = g - b*POST;
  float x1=0.f,y1=0.f,x2=0.f,y2=0.f;
  if (i < (int)meta[32+b]){
    int j = (int)keep[b*POST+i];
    int o = b*PRE + j;
    x1=tb[o]; y1=tb[NB*PRE+o]; x2=tb[2*NB*PRE+o]; y2=tb[3*NB*PRE+o];
  }
  float* op = out + (size_t)g*5;
  op[0]=(float)b; op[1]=x1; op[2]=y1; op[3]=x2; op[4]=y2;
}

extern "C" void kernel_launch(void* const* d_in, const int* in_sizes, int n_in,
                              void* d_out, int out_size, void* d_ws, size_t ws_size,
                              hipStream_t stream){
  (void)in_sizes; (void)n_in; (void)out_size; (void)ws_size;
  const float* scores = (const float*)d_in[0];
  const float* deltas = (const float*)d_in[1];
  const float* iminfo = (const float*)d_in[2];
  float* out = (float*)d_out;
  char* ws = (char*)d_ws;

  uint32_t* hist  = (uint32_t*)(ws + OFF_HIST);
  uint32_t* meta  = (uint32_t*)(ws + OFF_META);
  uint64_t* cand  = (uint64_t*)(ws + OFF_CAND);
  float*    tb    = (float*)   (ws + OFF_TB);
  uint32_t* keep  = (uint32_t*)(ws + OFF_KEEP);
  uint64_t* pres  = (uint64_t*)(ws + OFF_PRES);
  uint64_t* Mm    = (uint64_t*)(ws + OFF_M);

  hipMemsetAsync(ws + OFF_HIST, 0, SZ_HIST + SZ_META, stream);
  hipMemsetAsync(ws + OFF_CAND, 0xFF, SZ_CAND, stream);

  prep_k    <<<(NB*NTOT+255)/256, 256, 0, stream>>>(scores, hist);
  scanhist_k<<<NB, 1024, 0, stream>>>(hist, meta);
  gather_k  <<<(NB*NTOT+255)/256, 256, 0, stream>>>(scores, meta, cand);
  bsort_k   <<<NB, 1024, 0, stream>>>(cand);
  extract_k <<<(NB*PRE+255)/256, 256, 0, stream>>>(cand, deltas, iminfo, tb);
  for (int ph=0; ph<NPH; ph++){
    int base = ph*CHUNK;
    cross_k<<<dim3(CHUNK/256, NB), 256, 0, stream>>>(tb, keep, meta, pres, base);
    intra_k<<<dim3(CHUNK/8,   NB), 256, 0, stream>>>(tb, Mm, base);
    scan_k <<<NB, 64, 0, stream>>>(Mm, pres, keep, meta, base);
  }
  finalize_k<<<(NB*POST+255)/256, 256, 0, stream>>>(tb, keep, meta, out);
}

// Round 9
// 4664.820 us; speedup vs baseline: 6.7697x; 1.7030x over previous
//
#include <hip/hip_runtime.h>
#include <stdint.h>
#include <math.h>

#define NB   16
#define HF   128
#define WF   128
#define NA   9
#define HW   (HF*WF)          // 16384
#define NTOT (HW*NA)          // 147456
#define PRE  12000
#define POST 2000
#define CAP  16384
#define CHUNK 2048
#define NPH  6

// ws layout (bytes)
#define OFF_HIST  0u
#define SZ_HIST   (NB*65536u*4u)            // 4,194,304
#define OFF_META  (OFF_HIST + SZ_HIST)
#define SZ_META   4096u   // words: [0..15] cutoff | [32..47] nk | [256+b*16] gather count (64B-padded)
#define OFF_CAND  (OFF_META + SZ_META)
#define SZ_CAND   (NB*CAP*8u)               // 2,097,152
#define OFF_TB    (OFF_CAND + SZ_CAND)
#define SZ_TB     (5u*NB*PRE*4u)            // 3,840,000
#define OFF_KEEP  (OFF_TB + SZ_TB)
#define SZ_KEEP   (NB*POST*4u)              // 128,000
#define OFF_PRES  (OFF_KEEP + SZ_KEEP)
#define SZ_PRES   (NB*32u*8u)               // 4,096
#define OFF_M     (OFF_PRES + SZ_PRES)
#define SZ_M      ((size_t)NB*CHUNK*32u*8u) // 8,388,608

#define M_CNT(b)  (256 + (b)*16)

// base anchors = classic py-faster-rcnn table minus 1 (base [0,0,15,15]); a8.y2=359.
__constant__ float c_ax1[NA] = {-84.f,-176.f,-360.f,-56.f,-120.f,-248.f,-36.f,-80.f,-168.f};
__constant__ float c_ay1[NA] = {-40.f,-88.f,-184.f,-56.f,-120.f,-248.f,-80.f,-168.f,-344.f};
__constant__ float c_ax2[NA] = { 99.f, 191.f, 375.f, 71.f, 135.f, 263.f, 51.f, 95.f, 183.f};
__constant__ float c_ay2[NA] = { 55.f, 103.f, 199.f, 71.f, 135.f, 263.f, 95.f, 183.f, 359.f};

__device__ __forceinline__ uint32_t score_key(float f){
  uint32_t b = __float_as_uint(f);
  uint32_t u = (b & 0x80000000u) ? ~b : (b | 0x80000000u);
  return ~u;   // ascending key = descending score; idx in low bits -> stable ties
}

__device__ __forceinline__ bool iou_gt(float ax1,float ay1,float ax2,float ay2,float aa,
                                       float bx1,float by1,float bx2,float by2,float ba){
  float xx1 = fmaxf(ax1,bx1);
  float yy1 = fmaxf(ay1,by1);
  float xx2 = fminf(ax2,bx2);
  float yy2 = fminf(ay2,by2);
  float w = fmaxf(__fadd_rn(__fsub_rn(xx2,xx1),1.0f), 0.0f);
  float h = fmaxf(__fadd_rn(__fsub_rn(yy2,yy1),1.0f), 0.0f);
  float inter = __fmul_rn(w,h);
  float denom = __fsub_rn(__fadd_rn(aa,ba), inter);
  float iou   = __fdiv_rn(inter, denom);
  return iou > 0.7f;
}

// -------- pass 1: histogram of score keys (top 16 bits) --------
__global__ void prep_k(const float* __restrict__ scores, uint32_t* __restrict__ hist){
  int g = blockIdx.x*256 + threadIdx.x;
  if (g >= NB*NTOT) return;
  int hw = g & (HW-1);
  int t  = g >> 14;
  int ch = t % NA;
  int b  = t / NA;
  float s = scores[((size_t)(b*2*NA + NA + ch) << 14) + hw];
  uint32_t k = score_key(s);
  atomicAdd(&hist[((uint32_t)b<<16) + (k>>16)], 1u);
}

// -------- pass 2: find cutoff bucket per batch --------
__global__ __launch_bounds__(1024) void scanhist_k(const uint32_t* __restrict__ hist,
                                                   uint32_t* __restrict__ meta){
  int b = blockIdx.x, t = threadIdx.x;
  const uint32_t* hh = hist + ((uint32_t)b<<16);
  int base = t<<6;
  uint32_t s=0;
  for (int i=0;i<64;i++) s += hh[base+i];
  __shared__ uint32_t part[1024];
  part[t]=s; __syncthreads();
  for (int off=1; off<1024; off<<=1){
    uint32_t v = (t>=off)? part[t-off] : 0u;
    __syncthreads();
    part[t] += v;
    __syncthreads();
  }
  uint32_t incl = part[t], excl = incl - s;
  if (excl < PRE && incl >= PRE){
    uint32_t run = excl;
    for (int i=0;i<64;i++){
      run += hh[base+i];
      if (run >= PRE){ meta[b] = (uint32_t)(base+i); break; }
    }
  }
}

// -------- pass 3: gather (block-aggregated atomics; 1 atomic/block, padded counters) --------
__global__ __launch_bounds__(256) void gather_k(const float* __restrict__ scores,
                                                uint32_t* __restrict__ meta,
                                                uint64_t* __restrict__ cand){
  int g = blockIdx.x*256 + threadIdx.x;      // grid exact: NB*NTOT/256 blocks; b uniform per block
  int hw = g & (HW-1);
  int t  = g >> 14;
  int ch = t % NA;
  int b  = t / NA;
  float s = scores[((size_t)(b*2*NA + NA + ch) << 14) + hw];
  uint32_t k = score_key(s);
  bool sel = (k>>16) <= meta[b];
  unsigned long long m = __ballot(sel);
  int wid  = threadIdx.x >> 6;
  int lane = threadIdx.x & 63;
  __shared__ uint32_t woff[4];
  __shared__ uint32_t sbase;
  if (lane==0) woff[wid] = __popcll(m);
  __syncthreads();
  if (threadIdx.x==0){
    uint32_t a=0;
    #pragma unroll
    for (int i=0;i<4;i++){ uint32_t c=woff[i]; woff[i]=a; a+=c; }
    sbase = a ? atomicAdd(&meta[M_CNT(b)], a) : 0u;
  }
  __syncthreads();
  if (sel){
    uint32_t pos = sbase + woff[wid] + (uint32_t)__popcll(m & ((1ULL<<lane)-1ULL));
    if (pos < CAP){
      uint32_t idx = (uint32_t)hw*NA + (uint32_t)ch;
      cand[((size_t)b<<14) + pos] = ((uint64_t)k << 18) | (uint64_t)idx;
    }
  }
}

// ======== pass 4: bitonic sort, decomposed (identical (k,j) network) ========
// phase A: per-2048-chunk full sort (k=2..2048) in LDS
__global__ __launch_bounds__(256) void bsort_local_k(uint64_t* __restrict__ buf){
  __shared__ uint64_t S[2048];
  int blk = blockIdx.x;                 // NB*8 blocks
  int b = blk>>3, chunk = blk&7;
  uint64_t* A_ = buf + ((size_t)b<<14) + ((size_t)chunk<<11);
  int t = threadIdx.x;
  int gbase = chunk<<11;                // index within batch array
  for (int i=t;i<2048;i+=256) S[i]=A_[i];
  __syncthreads();
  for (unsigned k=2;k<=2048u;k<<=1){
    for (unsigned j=k>>1;j>0;j>>=1){
      for (int i=t;i<2048;i+=256){
        int l = i ^ (int)j;
        if (l > i){
          bool asc = (((gbase+i) & (int)k)==0);
          uint64_t a=S[i], c=S[l];
          bool sw = asc ? (a>c) : (a<c);
          if (sw){ S[i]=c; S[l]=a; }
        }
      }
      __syncthreads();
    }
  }
  for (int i=t;i<2048;i+=256) A_[i]=S[i];
}

// phase B: one global compare-exchange stage (j >= 2048)
__global__ __launch_bounds__(256) void bsort_pass_k(uint64_t* __restrict__ buf, int k, int j){
  int p = blockIdx.x*256 + threadIdx.x;   // NB*8192 pairs
  int b = p >> 13;
  int q = p & 8191;
  int i = ((q & ~(j-1))<<1) | (q & (j-1));
  int l = i + j;
  uint64_t* A_ = buf + ((size_t)b<<14);
  uint64_t a=A_[i], c=A_[l];
  bool asc = ((i & k)==0);
  bool sw = asc ? (a>c) : (a<c);
  if (sw){ A_[i]=c; A_[l]=a; }
}

// phase C: finish stages j<=1024 for merge step k, per 2048 chunk in LDS
__global__ __launch_bounds__(256) void bsort_finish_k(uint64_t* __restrict__ buf, int k){
  __shared__ uint64_t S[2048];
  int blk = blockIdx.x;
  int b = blk>>3, chunk = blk&7;
  uint64_t* A_ = buf + ((size_t)b<<14) + ((size_t)chunk<<11);
  int t = threadIdx.x;
  bool asc = (((chunk<<11) & k)==0);      // uniform per chunk (k>=4096)
  for (int i=t;i<2048;i+=256) S[i]=A_[i];
  __syncthreads();
  for (unsigned j=1024;j>0;j>>=1){
    for (int i=t;i<2048;i+=256){
      int l = i ^ (int)j;
      if (l > i){
        uint64_t a=S[i], c=S[l];
        bool sw = asc ? (a>c) : (a<c);
        if (sw){ S[i]=c; S[l]=a; }
      }
    }
    __syncthreads();
  }
  for (int i=t;i<2048;i+=256) A_[i]=S[i];
}

// -------- pass 5: decode top-12000 boxes (exact f32 ref arithmetic) --------
__global__ void extract_k(const uint64_t* __restrict__ cand2,
                          const float* __restrict__ deltas,
                          const float* __restrict__ iminfo,
                          float* __restrict__ tb){
  int g = blockIdx.x*256 + threadIdx.x;
  if (g >= NB*PRE) return;
  int b = g / PRE, j = g - b*PRE;
  uint64_t K = cand2[((size_t)b<<14) + j];
  uint32_t idx = (uint32_t)K & 0x3FFFFu;
  int ch = (int)(idx % NA);
  int hw = (int)(idx / NA);
  int w  = hw & (WF-1);
  int h  = hw >> 7;
  float sx = (float)(w*16), sy = (float)(h*16);
  float ax1 = c_ax1[ch]+sx, ay1 = c_ay1[ch]+sy, ax2 = c_ax2[ch]+sx, ay2 = c_ay2[ch]+sy;
  const float* dp = deltas + ((size_t)(b*4*NA + ch*4) << 14) + hw;
  float dx = dp[0], dy = dp[HW], dwv = dp[2*HW], dhv = dp[3*HW];
  float aw  = __fadd_rn(__fsub_rn(ax2,ax1),1.f);
  float ah  = __fadd_rn(__fsub_rn(ay2,ay1),1.f);
  float acx = __fadd_rn(ax1, __fmul_rn(0.5f,aw));
  float acy = __fadd_rn(ay1, __fmul_rn(0.5f,ah));
  float pcx = __fadd_rn(__fmul_rn(dx,aw), acx);
  float pcy = __fadd_rn(__fmul_rn(dy,ah), acy);
  float ew  = (float)exp((double)dwv);
  float eh  = (float)exp((double)dhv);
  float pw  = __fmul_rn(ew, aw);
  float ph  = __fmul_rn(eh, ah);
  float hx  = __fmul_rn(0.5f,pw), hy = __fmul_rn(0.5f,ph);
  float x1 = __fsub_rn(pcx,hx), y1 = __fsub_rn(pcy,hy);
  float x2 = __fadd_rn(pcx,hx), y2 = __fadd_rn(pcy,hy);
  float maxx = __fsub_rn(iminfo[b*3+1],1.f);
  float maxy = __fsub_rn(iminfo[b*3+0],1.f);
  x1 = fminf(fmaxf(x1,0.f),maxx); y1 = fminf(fmaxf(y1,0.f),maxy);
  x2 = fminf(fmaxf(x2,0.f),maxx); y2 = fminf(fmaxf(y2,0.f),maxy);
  float area = __fmul_rn(__fadd_rn(__fsub_rn(x2,x1),1.f), __fadd_rn(__fsub_rn(y2,y1),1.f));
  int o = b*PRE + j;
  tb[o]            = x1;
  tb[NB*PRE + o]   = y1;
  tb[2*NB*PRE + o] = x2;
  tb[3*NB*PRE + o] = y2;
  tb[4*NB*PRE + o] = area;
}

// -------- NMS phase a: chunk candidates vs already-kept boxes --------
__global__ void cross_k(const float* __restrict__ tb, const uint32_t* __restrict__ keep,
                        const uint32_t* __restrict__ meta, uint64_t* __restrict__ presup,
                        int base){
  int b  = blockIdx.y;
  int jl = blockIdx.x*256 + threadIdx.x;
  int j  = base + jl;
  bool valid = (j < PRE);
  float x1=0,y1=0,x2=0,y2=0,ar=0;
  if (valid){
    int o = b*PRE + j;
    x1=tb[o]; y1=tb[NB*PRE+o]; x2=tb[2*NB*PRE+o]; y2=tb[3*NB*PRE+o]; ar=tb[4*NB*PRE+o];
  }
  int nk = (int)meta[32+b];
  __shared__ float kx1[256],ky1[256],kx2[256],ky2[256],kar[256];
  bool supp = !valid;
  for (int k0=0; k0<nk; k0+=256){
    int kk = k0 + threadIdx.x;
    if (kk < nk){
      int kj = (int)keep[b*POST+kk];
      int o = b*PRE + kj;
      kx1[threadIdx.x]=tb[o]; ky1[threadIdx.x]=tb[NB*PRE+o];
      kx2[threadIdx.x]=tb[2*NB*PRE+o]; ky2[threadIdx.x]=tb[3*NB*PRE+o];
      kar[threadIdx.x]=tb[4*NB*PRE+o];
    }
    __syncthreads();
    int lim = min(256, nk-k0);
    if (!supp){
      for (int q=0;q<lim;q++){
        if (iou_gt(kx1[q],ky1[q],kx2[q],ky2[q],kar[q], x1,y1,x2,y2,ar)){ supp=true; break; }
      }
    }
    __syncthreads();
  }
  unsigned long long m = __ballot(supp);
  if ((threadIdx.x & 63)==0) presup[b*32 + (jl>>6)] = m;
}

// -------- NMS phase b: intra-chunk pairwise bit-matrix --------
__global__ void intra_k(const float* __restrict__ tb, uint64_t* __restrict__ Mm, int base){
  int b  = blockIdx.y;
  int il = blockIdx.x*8 + (threadIdx.x>>5);
  int jw = threadIdx.x & 31;
  __shared__ float sx1[CHUNK],sy1[CHUNK],sx2[CHUNK],sy2[CHUNK],sar[CHUNK]; // 40 KB
  for (int s = threadIdx.x; s < CHUNK; s += 256){
    int j = base + s;
    if (j < PRE){
      int o = b*PRE + j;
      sx1[s]=tb[o]; sy1[s]=tb[NB*PRE+o]; sx2[s]=tb[2*NB*PRE+o]; sy2[s]=tb[3*NB*PRE+o]; sar[s]=tb[4*NB*PRE+o];
    } else { sx1[s]=0.f; sy1[s]=0.f; sx2[s]=-10.f; sy2[s]=-10.f; sar[s]=1.f; }
  }
  __syncthreads();
  size_t mo = (((size_t)b*CHUNK) + (size_t)il)*32 + jw;
  int i = base + il;
  if (i >= PRE)          { Mm[mo] = 0; return; }
  if ((jw+1)*64 <= il)   { Mm[mo] = 0; return; }
  float x1=sx1[il], y1=sy1[il], x2=sx2[il], y2=sy2[il], ar=sar[il];
  uint64_t bits = 0;
  int jbase = jw*64;
  for (int q=0;q<64;q++){
    int jl = jbase+q;
    bool s = (base+jl < PRE) && iou_gt(x1,y1,x2,y2,ar, sx1[jl],sy1[jl],sx2[jl],sy2[jl],sar[jl]);
    bits |= ((uint64_t)s) << q;
  }
  Mm[mo] = bits;
}

// -------- NMS phase c: bit-serial greedy scan (1 wave per batch) --------
__global__ __launch_bounds__(64) void scan_k(const uint64_t* __restrict__ Mm,
                                             const uint64_t* __restrict__ presup,
                                             uint32_t* __restrict__ keep,
                                             uint32_t* __restrict__ meta,
                                             int base){
  int b = blockIdx.x;
  int l = threadIdx.x;
  uint64_t acc = (l<32) ? presup[b*32+l] : ~0ULL;
  int nk = (int)meta[32+b];
  const uint64_t* Mb = Mm + (size_t)b*CHUNK*32;
  for (int jl=0; jl<CHUNK; jl++){
    if (nk >= POST) break;
    uint64_t wv = __shfl(acc, jl>>6);
    if (!((wv >> (jl&63)) & 1ULL)){
      if (l==0) keep[b*POST+nk] = (uint32_t)(base + jl);
      nk++;
      if (l<32) acc |= Mb[(size_t)jl*32 + l];
    }
  }
  if (l==0) meta[32+b] = (uint32_t)nk;
}

// -------- output (f32) --------
__global__ void finalize_k(const float* __restrict__ tb, const uint32_t* __restrict__ keep,
                           const uint32_t* __restrict__ meta, float* __restrict__ out){
  int g = blockIdx.x*256 + threadIdx.x;
  if (g >= NB*POST) return;
  int b = g / POST, i = g - b*POST;
  float x1=0.f,y1=0.f,x2=0.f,y2=0.f;
  if (i < (int)meta[32+b]){
    int j = (int)keep[b*POST+i];
    int o = b*PRE + j;
    x1=tb[o]; y1=tb[NB*PRE+o]; x2=tb[2*NB*PRE+o]; y2=tb[3*NB*PRE+o];
  }
  float* op = out + (size_t)g*5;
  op[0]=(float)b; op[1]=x1; op[2]=y1; op[3]=x2; op[4]=y2;
}

extern "C" void kernel_launch(void* const* d_in, const int* in_sizes, int n_in,
                              void* d_out, int out_size, void* d_ws, size_t ws_size,
                              hipStream_t stream){
  (void)in_sizes; (void)n_in; (void)out_size; (void)ws_size;
  const float* scores = (const float*)d_in[0];
  const float* deltas = (const float*)d_in[1];
  const float* iminfo = (const float*)d_in[2];
  float* out = (float*)d_out;
  char* ws = (char*)d_ws;

  uint32_t* hist  = (uint32_t*)(ws + OFF_HIST);
  uint32_t* meta  = (uint32_t*)(ws + OFF_META);
  uint64_t* cand  = (uint64_t*)(ws + OFF_CAND);
  float*    tb    = (float*)   (ws + OFF_TB);
  uint32_t* keep  = (uint32_t*)(ws + OFF_KEEP);
  uint64_t* pres  = (uint64_t*)(ws + OFF_PRES);
  uint64_t* Mm    = (uint64_t*)(ws + OFF_M);

  hipMemsetAsync(ws + OFF_HIST, 0, SZ_HIST + SZ_META, stream);
  hipMemsetAsync(ws + OFF_CAND, 0xFF, SZ_CAND, stream);

  prep_k    <<<(NB*NTOT+255)/256, 256, 0, stream>>>(scores, hist);
  scanhist_k<<<NB, 1024, 0, stream>>>(hist, meta);
  gather_k  <<<NB*NTOT/256, 256, 0, stream>>>(scores, meta, cand);

  bsort_local_k<<<NB*8, 256, 0, stream>>>(cand);
  for (int k=4096; k<=16384; k<<=1){
    for (int j=k>>1; j>=2048; j>>=1)
      bsort_pass_k<<<NB*8192/256, 256, 0, stream>>>(cand, k, j);
    bsort_finish_k<<<NB*8, 256, 0, stream>>>(cand, k);
  }

  extract_k <<<(NB*PRE+255)/256, 256, 0, stream>>>(cand, deltas, iminfo, tb);
  for (int ph=0; ph<NPH; ph++){
    int base = ph*CHUNK;
    cross_k<<<dim3(CHUNK/256, NB), 256, 0, stream>>>(tb, keep, meta, pres, base);
    intra_k<<<dim3(CHUNK/8,   NB), 256, 0, stream>>>(tb, Mm, base);
    scan_k <<<NB, 64, 0, stream>>>(Mm, pres, keep, meta, base);
  }
  finalize_k<<<(NB*POST+255)/256, 256, 0, stream>>>(tb, keep, meta, out);
}

// Round 10
// 4460.143 us; speedup vs baseline: 7.0804x; 1.0459x over previous
//
#include <hip/hip_runtime.h>
#include <stdint.h>
#include <math.h>

#define NB   16
#define HF   128
#define WF   128
#define NA   9
#define HW   (HF*WF)          // 16384
#define NTOT (HW*NA)          // 147456
#define PRE  12000
#define POST 2000
#define CAP  16384
#define CHUNK 2048
#define NPH  6

// ws layout (bytes)
#define OFF_HIST  0u
#define SZ_HIST   (NB*65536u*4u)            // 4,194,304
#define OFF_META  (OFF_HIST + SZ_HIST)
#define SZ_META   4096u   // words: [0..15] cutoff | [32..47] nk | [256+b*16] gather count (64B-padded)
#define OFF_CAND  (OFF_META + SZ_META)
#define SZ_CAND   (NB*CAP*8u)               // 2,097,152
#define OFF_TB    (OFF_CAND + SZ_CAND)
#define SZ_TB     (5u*NB*PRE*4u)            // 3,840,000
#define OFF_KEEP  (OFF_TB + SZ_TB)
#define SZ_KEEP   (NB*POST*4u)              // 128,000
#define OFF_PRES  (OFF_KEEP + SZ_KEEP)
#define SZ_PRES   (NB*32u*8u)               // 4,096
#define OFF_M     (OFF_PRES + SZ_PRES)
#define SZ_M      ((size_t)NB*CHUNK*32u*8u) // 8,388,608

#define M_CNT(b)  (256 + (b)*16)

// base anchors = classic py-faster-rcnn table minus 1 (base [0,0,15,15]); a8.y2=359.
__constant__ float c_ax1[NA] = {-84.f,-176.f,-360.f,-56.f,-120.f,-248.f,-36.f,-80.f,-168.f};
__constant__ float c_ay1[NA] = {-40.f,-88.f,-184.f,-56.f,-120.f,-248.f,-80.f,-168.f,-344.f};
__constant__ float c_ax2[NA] = { 99.f, 191.f, 375.f, 71.f, 135.f, 263.f, 51.f, 95.f, 183.f};
__constant__ float c_ay2[NA] = { 55.f, 103.f, 199.f, 71.f, 135.f, 263.f, 95.f, 183.f, 359.f};

__device__ __forceinline__ uint32_t score_key(float f){
  uint32_t b = __float_as_uint(f);
  uint32_t u = (b & 0x80000000u) ? ~b : (b | 0x80000000u);
  return ~u;   // ascending key = descending score; idx in low bits -> stable ties
}

__device__ __forceinline__ bool iou_gt(float ax1,float ay1,float ax2,float ay2,float aa,
                                       float bx1,float by1,float bx2,float by2,float ba){
  float xx1 = fmaxf(ax1,bx1);
  float yy1 = fmaxf(ay1,by1);
  float xx2 = fminf(ax2,bx2);
  float yy2 = fminf(ay2,by2);
  float w = fmaxf(__fadd_rn(__fsub_rn(xx2,xx1),1.0f), 0.0f);
  float h = fmaxf(__fadd_rn(__fsub_rn(yy2,yy1),1.0f), 0.0f);
  float inter = __fmul_rn(w,h);
  float denom = __fsub_rn(__fadd_rn(aa,ba), inter);
  float iou   = __fdiv_rn(inter, denom);
  return iou > 0.7f;
}

// -------- pass 1: histogram of score keys (top 16 bits) --------
__global__ void prep_k(const float* __restrict__ scores, uint32_t* __restrict__ hist){
  int g = blockIdx.x*256 + threadIdx.x;
  if (g >= NB*NTOT) return;
  int hw = g & (HW-1);
  int t  = g >> 14;
  int ch = t % NA;
  int b  = t / NA;
  float s = scores[((size_t)(b*2*NA + NA + ch) << 14) + hw];
  uint32_t k = score_key(s);
  atomicAdd(&hist[((uint32_t)b<<16) + (k>>16)], 1u);
}

// -------- pass 2: find cutoff bucket per batch --------
__global__ __launch_bounds__(1024) void scanhist_k(const uint32_t* __restrict__ hist,
                                                   uint32_t* __restrict__ meta){
  int b = blockIdx.x, t = threadIdx.x;
  const uint32_t* hh = hist + ((uint32_t)b<<16);
  int base = t<<6;
  uint32_t s=0;
  for (int i=0;i<64;i++) s += hh[base+i];
  __shared__ uint32_t part[1024];
  part[t]=s; __syncthreads();
  for (int off=1; off<1024; off<<=1){
    uint32_t v = (t>=off)? part[t-off] : 0u;
    __syncthreads();
    part[t] += v;
    __syncthreads();
  }
  uint32_t incl = part[t], excl = incl - s;
  if (excl < PRE && incl >= PRE){
    uint32_t run = excl;
    for (int i=0;i<64;i++){
      run += hh[base+i];
      if (run >= PRE){ meta[b] = (uint32_t)(base+i); break; }
    }
  }
}

// -------- pass 3: gather (block-aggregated atomics) --------
__global__ __launch_bounds__(256) void gather_k(const float* __restrict__ scores,
                                                uint32_t* __restrict__ meta,
                                                uint64_t* __restrict__ cand){
  int g = blockIdx.x*256 + threadIdx.x;
  int hw = g & (HW-1);
  int t  = g >> 14;
  int ch = t % NA;
  int b  = t / NA;
  float s = scores[((size_t)(b*2*NA + NA + ch) << 14) + hw];
  uint32_t k = score_key(s);
  bool sel = (k>>16) <= meta[b];
  unsigned long long m = __ballot(sel);
  int wid  = threadIdx.x >> 6;
  int lane = threadIdx.x & 63;
  __shared__ uint32_t woff[4];
  __shared__ uint32_t sbase;
  if (lane==0) woff[wid] = __popcll(m);
  __syncthreads();
  if (threadIdx.x==0){
    uint32_t a=0;
    #pragma unroll
    for (int i=0;i<4;i++){ uint32_t c=woff[i]; woff[i]=a; a+=c; }
    sbase = a ? atomicAdd(&meta[M_CNT(b)], a) : 0u;
  }
  __syncthreads();
  if (sel){
    uint32_t pos = sbase + woff[wid] + (uint32_t)__popcll(m & ((1ULL<<lane)-1ULL));
    if (pos < CAP){
      uint32_t idx = (uint32_t)hw*NA + (uint32_t)ch;
      cand[((size_t)b<<14) + pos] = ((uint64_t)k << 18) | (uint64_t)idx;
    }
  }
}

// ======== pass 4: bitonic sort, decomposed (identical (k,j) network) ========
__global__ __launch_bounds__(256) void bsort_local_k(uint64_t* __restrict__ buf){
  __shared__ uint64_t S[2048];
  int blk = blockIdx.x;
  int b = blk>>3, chunk = blk&7;
  uint64_t* A_ = buf + ((size_t)b<<14) + ((size_t)chunk<<11);
  int t = threadIdx.x;
  int gbase = chunk<<11;
  for (int i=t;i<2048;i+=256) S[i]=A_[i];
  __syncthreads();
  for (unsigned k=2;k<=2048u;k<<=1){
    for (unsigned j=k>>1;j>0;j>>=1){
      for (int i=t;i<2048;i+=256){
        int l = i ^ (int)j;
        if (l > i){
          bool asc = (((gbase+i) & (int)k)==0);
          uint64_t a=S[i], c=S[l];
          bool sw = asc ? (a>c) : (a<c);
          if (sw){ S[i]=c; S[l]=a; }
        }
      }
      __syncthreads();
    }
  }
  for (int i=t;i<2048;i+=256) A_[i]=S[i];
}

__global__ __launch_bounds__(256) void bsort_pass_k(uint64_t* __restrict__ buf, int k, int j){
  int p = blockIdx.x*256 + threadIdx.x;
  int b = p >> 13;
  int q = p & 8191;
  int i = ((q & ~(j-1))<<1) | (q & (j-1));
  int l = i + j;
  uint64_t* A_ = buf + ((size_t)b<<14);
  uint64_t a=A_[i], c=A_[l];
  bool asc = ((i & k)==0);
  bool sw = asc ? (a>c) : (a<c);
  if (sw){ A_[i]=c; A_[l]=a; }
}

__global__ __launch_bounds__(256) void bsort_finish_k(uint64_t* __restrict__ buf, int k){
  __shared__ uint64_t S[2048];
  int blk = blockIdx.x;
  int b = blk>>3, chunk = blk&7;
  uint64_t* A_ = buf + ((size_t)b<<14) + ((size_t)chunk<<11);
  int t = threadIdx.x;
  bool asc = (((chunk<<11) & k)==0);
  for (int i=t;i<2048;i+=256) S[i]=A_[i];
  __syncthreads();
  for (unsigned j=1024;j>0;j>>=1){
    for (int i=t;i<2048;i+=256){
      int l = i ^ (int)j;
      if (l > i){
        uint64_t a=S[i], c=S[l];
        bool sw = asc ? (a>c) : (a<c);
        if (sw){ S[i]=c; S[l]=a; }
      }
    }
    __syncthreads();
  }
  for (int i=t;i<2048;i+=256) A_[i]=S[i];
}

// -------- pass 5: decode top-12000 boxes (exact f32 ref arithmetic) --------
__global__ void extract_k(const uint64_t* __restrict__ cand2,
                          const float* __restrict__ deltas,
                          const float* __restrict__ iminfo,
                          float* __restrict__ tb){
  int g = blockIdx.x*256 + threadIdx.x;
  if (g >= NB*PRE) return;
  int b = g / PRE, j = g - b*PRE;
  uint64_t K = cand2[((size_t)b<<14) + j];
  uint32_t idx = (uint32_t)K & 0x3FFFFu;
  int ch = (int)(idx % NA);
  int hw = (int)(idx / NA);
  int w  = hw & (WF-1);
  int h  = hw >> 7;
  float sx = (float)(w*16), sy = (float)(h*16);
  float ax1 = c_ax1[ch]+sx, ay1 = c_ay1[ch]+sy, ax2 = c_ax2[ch]+sx, ay2 = c_ay2[ch]+sy;
  const float* dp = deltas + ((size_t)(b*4*NA + ch*4) << 14) + hw;
  float dx = dp[0], dy = dp[HW], dwv = dp[2*HW], dhv = dp[3*HW];
  float aw  = __fadd_rn(__fsub_rn(ax2,ax1),1.f);
  float ah  = __fadd_rn(__fsub_rn(ay2,ay1),1.f);
  float acx = __fadd_rn(ax1, __fmul_rn(0.5f,aw));
  float acy = __fadd_rn(ay1, __fmul_rn(0.5f,ah));
  float pcx = __fadd_rn(__fmul_rn(dx,aw), acx);
  float pcy = __fadd_rn(__fmul_rn(dy,ah), acy);
  float ew  = (float)exp((double)dwv);
  float eh  = (float)exp((double)dhv);
  float pw  = __fmul_rn(ew, aw);
  float ph  = __fmul_rn(eh, ah);
  float hx  = __fmul_rn(0.5f,pw), hy = __fmul_rn(0.5f,ph);
  float x1 = __fsub_rn(pcx,hx), y1 = __fsub_rn(pcy,hy);
  float x2 = __fadd_rn(pcx,hx), y2 = __fadd_rn(pcy,hy);
  float maxx = __fsub_rn(iminfo[b*3+1],1.f);
  float maxy = __fsub_rn(iminfo[b*3+0],1.f);
  x1 = fminf(fmaxf(x1,0.f),maxx); y1 = fminf(fmaxf(y1,0.f),maxy);
  x2 = fminf(fmaxf(x2,0.f),maxx); y2 = fminf(fmaxf(y2,0.f),maxy);
  float area = __fmul_rn(__fadd_rn(__fsub_rn(x2,x1),1.f), __fadd_rn(__fsub_rn(y2,y1),1.f));
  int o = b*PRE + j;
  tb[o]            = x1;
  tb[NB*PRE + o]   = y1;
  tb[2*NB*PRE + o] = x2;
  tb[3*NB*PRE + o] = y2;
  tb[4*NB*PRE + o] = area;
}

// -------- NMS phase a: chunk candidates vs already-kept boxes --------
__global__ void cross_k(const float* __restrict__ tb, const uint32_t* __restrict__ keep,
                        const uint32_t* __restrict__ meta, uint64_t* __restrict__ presup,
                        int base){
  int b  = blockIdx.y;
  int jl = blockIdx.x*256 + threadIdx.x;
  int j  = base + jl;
  bool valid = (j < PRE);
  float x1=0,y1=0,x2=0,y2=0,ar=0;
  if (valid){
    int o = b*PRE + j;
    x1=tb[o]; y1=tb[NB*PRE+o]; x2=tb[2*NB*PRE+o]; y2=tb[3*NB*PRE+o]; ar=tb[4*NB*PRE+o];
  }
  int nk = (int)meta[32+b];
  __shared__ float kx1[256],ky1[256],kx2[256],ky2[256],kar[256];
  bool supp = !valid;
  for (int k0=0; k0<nk; k0+=256){
    int kk = k0 + threadIdx.x;
    if (kk < nk){
      int kj = (int)keep[b*POST+kk];
      int o = b*PRE + kj;
      kx1[threadIdx.x]=tb[o]; ky1[threadIdx.x]=tb[NB*PRE+o];
      kx2[threadIdx.x]=tb[2*NB*PRE+o]; ky2[threadIdx.x]=tb[3*NB*PRE+o];
      kar[threadIdx.x]=tb[4*NB*PRE+o];
    }
    __syncthreads();
    int lim = min(256, nk-k0);
    if (!supp){
      for (int q=0;q<lim;q++){
        if (iou_gt(kx1[q],ky1[q],kx2[q],ky2[q],kar[q], x1,y1,x2,y2,ar)){ supp=true; break; }
      }
    }
    __syncthreads();
  }
  unsigned long long m = __ballot(supp);
  if ((threadIdx.x & 63)==0) presup[b*32 + (jl>>6)] = m;
}

// -------- NMS phase b: intra-chunk pairwise bit-matrix --------
__global__ void intra_k(const float* __restrict__ tb, uint64_t* __restrict__ Mm, int base){
  int b  = blockIdx.y;
  int il = blockIdx.x*8 + (threadIdx.x>>5);
  int jw = threadIdx.x & 31;
  __shared__ float sx1[CHUNK],sy1[CHUNK],sx2[CHUNK],sy2[CHUNK],sar[CHUNK]; // 40 KB
  for (int s = threadIdx.x; s < CHUNK; s += 256){
    int j = base + s;
    if (j < PRE){
      int o = b*PRE + j;
      sx1[s]=tb[o]; sy1[s]=tb[NB*PRE+o]; sx2[s]=tb[2*NB*PRE+o]; sy2[s]=tb[3*NB*PRE+o]; sar[s]=tb[4*NB*PRE+o];
    } else { sx1[s]=0.f; sy1[s]=0.f; sx2[s]=-10.f; sy2[s]=-10.f; sar[s]=1.f; }
  }
  __syncthreads();
  size_t mo = (((size_t)b*CHUNK) + (size_t)il)*32 + jw;
  int i = base + il;
  if (i >= PRE)          { Mm[mo] = 0; return; }
  if ((jw+1)*64 <= il)   { Mm[mo] = 0; return; }
  float x1=sx1[il], y1=sy1[il], x2=sx2[il], y2=sy2[il], ar=sar[il];
  uint64_t bits = 0;
  int jbase = jw*64;
  for (int q=0;q<64;q++){
    int jl = jbase+q;
    bool s = (base+jl < PRE) && iou_gt(x1,y1,x2,y2,ar, sx1[jl],sy1[jl],sx2[jl],sy2[jl],sar[jl]);
    bits |= ((uint64_t)s) << q;
  }
  Mm[mo] = bits;
}

// -------- NMS phase c: word-batched greedy scan (1 wave per batch) --------
// Cross-validated vs literal serial NMS (rounds 1-3: bit-identical keep lists).
__global__ __launch_bounds__(64) void scan_k(const uint64_t* __restrict__ Mm,
                                             const uint64_t* __restrict__ presup,
                                             uint32_t* __restrict__ keep,
                                             uint32_t* __restrict__ meta,
                                             int base){
  int b = blockIdx.x;
  int l = threadIdx.x;
  uint64_t acc = (l<32) ? presup[b*32+l] : ~0ULL;
  int nk = (int)meta[32+b];
  const uint64_t* Mb = Mm + (size_t)b*CHUNK*32;
  for (int w=0; w<32; w++){
    if (nk >= POST) break;
    uint64_t tile = Mb[(size_t)(w*64+l)*32 + w];   // lane l: word w of row (w*64+l)
    uint64_t cur  = __shfl(acc, w);
    uint64_t kmask = 0;
    while (cur != ~0ULL && nk < POST){
      int p = __ffsll((unsigned long long)(~cur)) - 1;
      if (l==0) keep[b*POST+nk] = (uint32_t)(base + w*64 + p);
      nk++;
      kmask |= (1ULL<<p);
      cur |= (1ULL<<p) | (uint64_t)__shfl(tile, p);  // row p suppresses within word w
    }
    // OR kept rows into acc (2-way MLP on the row loads)
    while (kmask){
      int p0 = __ffsll((unsigned long long)kmask) - 1; kmask &= kmask-1;
      int p1 = -1;
      if (kmask){ p1 = __ffsll((unsigned long long)kmask) - 1; kmask &= kmask-1; }
      uint64_t v0 = (l<32) ? Mb[(size_t)(w*64+p0)*32 + l] : 0ULL;
      uint64_t v1 = (p1>=0 && l<32) ? Mb[(size_t)(w*64+p1)*32 + l] : 0ULL;
      acc |= v0 | v1;
    }
  }
  if (l==0) meta[32+b] = (uint32_t)nk;
}

// -------- output (f32) --------
__global__ void finalize_k(const float* __restrict__ tb, const uint32_t* __restrict__ keep,
                           const uint32_t* __restrict__ meta, float* __restrict__ out){
  int g = blockIdx.x*256 + threadIdx.x;
  if (g >= NB*POST) return;
  int b = g / POST, i = g - b*POST;
  float x1=0.f,y1=0.f,x2=0.f,y2=0.f;
  if (i < (int)meta[32+b]){
    int j = (int)keep[b*POST+i];
    int o = b*PRE + j;
    x1=tb[o]; y1=tb[NB*PRE+o]; x2=tb[2*NB*PRE+o]; y2=tb[3*NB*PRE+o];
  }
  float* op = out + (size_t)g*5;
  op[0]=(float)b; op[1]=x1; op[2]=y1; op[3]=x2; op[4]=y2;
}

extern "C" void kernel_launch(void* const* d_in, const int* in_sizes, int n_in,
                              void* d_out, int out_size, void* d_ws, size_t ws_size,
                              hipStream_t stream){
  (void)in_sizes; (void)n_in; (void)out_size; (void)ws_size;
  const float* scores = (const float*)d_in[0];
  const float* deltas = (const float*)d_in[1];
  const float* iminfo = (const float*)d_in[2];
  float* out = (float*)d_out;
  char* ws = (char*)d_ws;

  uint32_t* hist  = (uint32_t*)(ws + OFF_HIST);
  uint32_t* meta  = (uint32_t*)(ws + OFF_META);
  uint64_t* cand  = (uint64_t*)(ws + OFF_CAND);
  float*    tb    = (float*)   (ws + OFF_TB);
  uint32_t* keep  = (uint32_t*)(ws + OFF_KEEP);
  uint64_t* pres  = (uint64_t*)(ws + OFF_PRES);
  uint64_t* Mm    = (uint64_t*)(ws + OFF_M);

  hipMemsetAsync(ws + OFF_HIST, 0, SZ_HIST + SZ_META, stream);
  hipMemsetAsync(ws + OFF_CAND, 0xFF, SZ_CAND, stream);

  prep_k    <<<(NB*NTOT+255)/256, 256, 0, stream>>>(scores, hist);
  scanhist_k<<<NB, 1024, 0, stream>>>(hist, meta);
  gather_k  <<<NB*NTOT/256, 256, 0, stream>>>(scores, meta, cand);

  bsort_local_k<<<NB*8, 256, 0, stream>>>(cand);
  for (int k=4096; k<=16384; k<<=1){
    for (int j=k>>1; j>=2048; j>>=1)
      bsort_pass_k<<<NB*8192/256, 256, 0, stream>>>(cand, k, j);
    bsort_finish_k<<<NB*8, 256, 0, stream>>>(cand, k);
  }

  extract_k <<<(NB*PRE+255)/256, 256, 0, stream>>>(cand, deltas, iminfo, tb);
  for (int ph=0; ph<NPH; ph++){
    int base = ph*CHUNK;
    cross_k<<<dim3(CHUNK/256, NB), 256, 0, stream>>>(tb, keep, meta, pres, base);
    intra_k<<<dim3(CHUNK/8,   NB), 256, 0, stream>>>(tb, Mm, base);
    scan_k <<<NB, 64, 0, stream>>>(Mm, pres, keep, meta, base);
  }
  finalize_k<<<(NB*POST+255)/256, 256, 0, stream>>>(tb, keep, meta, out);
}

// Round 11
// 4328.771 us; speedup vs baseline: 7.2953x; 1.0303x over previous
//
#include <hip/hip_runtime.h>
#include <stdint.h>
#include <math.h>

#define NB   16
#define HF   128
#define WF   128
#define NA   9
#define HW   (HF*WF)          // 16384
#define NTOT (HW*NA)          // 147456
#define PRE  12000
#define POST 2000
#define CAP  16384
#define CHUNK 2048
#define NPH  6

// ws layout (bytes)
#define OFF_HIST  0u
#define SZ_HIST   (NB*65536u*4u)            // 4,194,304
#define OFF_META  (OFF_HIST + SZ_HIST)
#define SZ_META   4096u   // words: [0..15] cutoff | [32..47] nk | [256+b*16] gather count (64B-padded)
#define OFF_CAND  (OFF_META + SZ_META)
#define SZ_CAND   (NB*CAP*8u)               // 2,097,152
#define OFF_TB    (OFF_CAND + SZ_CAND)
#define SZ_TB     (5u*NB*PRE*4u)            // 3,840,000
#define OFF_KEEP  (OFF_TB + SZ_TB)
#define SZ_KEEP   (NB*POST*4u)              // 128,000
#define OFF_PRES  (OFF_KEEP + SZ_KEEP)
#define SZ_PRES   (NB*32u*8u)               // 4,096
#define OFF_M     (OFF_PRES + SZ_PRES)
#define SZ_M      ((size_t)NB*CHUNK*32u*8u) // 8,388,608

#define M_CNT(b)  (256 + (b)*16)

// base anchors = classic py-faster-rcnn table minus 1 (base [0,0,15,15]); a8.y2=359.
__constant__ float c_ax1[NA] = {-84.f,-176.f,-360.f,-56.f,-120.f,-248.f,-36.f,-80.f,-168.f};
__constant__ float c_ay1[NA] = {-40.f,-88.f,-184.f,-56.f,-120.f,-248.f,-80.f,-168.f,-344.f};
__constant__ float c_ax2[NA] = { 99.f, 191.f, 375.f, 71.f, 135.f, 263.f, 51.f, 95.f, 183.f};
__constant__ float c_ay2[NA] = { 55.f, 103.f, 199.f, 71.f, 135.f, 263.f, 95.f, 183.f, 359.f};

__device__ __forceinline__ uint32_t score_key(float f){
  uint32_t b = __float_as_uint(f);
  uint32_t u = (b & 0x80000000u) ? ~b : (b | 0x80000000u);
  return ~u;   // ascending key = descending score; idx in low bits -> stable ties
}

__device__ __forceinline__ bool iou_gt(float ax1,float ay1,float ax2,float ay2,float aa,
                                       float bx1,float by1,float bx2,float by2,float ba){
  float xx1 = fmaxf(ax1,bx1);
  float yy1 = fmaxf(ay1,by1);
  float xx2 = fminf(ax2,bx2);
  float yy2 = fminf(ay2,by2);
  float w = fmaxf(__fadd_rn(__fsub_rn(xx2,xx1),1.0f), 0.0f);
  float h = fmaxf(__fadd_rn(__fsub_rn(yy2,yy1),1.0f), 0.0f);
  float inter = __fmul_rn(w,h);
  float denom = __fsub_rn(__fadd_rn(aa,ba), inter);
  float iou   = __fdiv_rn(inter, denom);
  return iou > 0.7f;
}

// -------- pass 1: histogram of score keys (top 16 bits) --------
__global__ void prep_k(const float* __restrict__ scores, uint32_t* __restrict__ hist){
  int g = blockIdx.x*256 + threadIdx.x;
  if (g >= NB*NTOT) return;
  int hw = g & (HW-1);
  int t  = g >> 14;
  int ch = t % NA;
  int b  = t / NA;
  float s = scores[((size_t)(b*2*NA + NA + ch) << 14) + hw];
  uint32_t k = score_key(s);
  atomicAdd(&hist[((uint32_t)b<<16) + (k>>16)], 1u);
}

// -------- pass 2: find cutoff bucket per batch --------
__global__ __launch_bounds__(1024) void scanhist_k(const uint32_t* __restrict__ hist,
                                                   uint32_t* __restrict__ meta){
  int b = blockIdx.x, t = threadIdx.x;
  const uint32_t* hh = hist + ((uint32_t)b<<16);
  int base = t<<6;
  uint32_t s=0;
  for (int i=0;i<64;i++) s += hh[base+i];
  __shared__ uint32_t part[1024];
  part[t]=s; __syncthreads();
  for (int off=1; off<1024; off<<=1){
    uint32_t v = (t>=off)? part[t-off] : 0u;
    __syncthreads();
    part[t] += v;
    __syncthreads();
  }
  uint32_t incl = part[t], excl = incl - s;
  if (excl < PRE && incl >= PRE){
    uint32_t run = excl;
    for (int i=0;i<64;i++){
      run += hh[base+i];
      if (run >= PRE){ meta[b] = (uint32_t)(base+i); break; }
    }
  }
}

// -------- pass 3: gather (block-aggregated atomics) --------
__global__ __launch_bounds__(256) void gather_k(const float* __restrict__ scores,
                                                uint32_t* __restrict__ meta,
                                                uint64_t* __restrict__ cand){
  int g = blockIdx.x*256 + threadIdx.x;
  int hw = g & (HW-1);
  int t  = g >> 14;
  int ch = t % NA;
  int b  = t / NA;
  float s = scores[((size_t)(b*2*NA + NA + ch) << 14) + hw];
  uint32_t k = score_key(s);
  bool sel = (k>>16) <= meta[b];
  unsigned long long m = __ballot(sel);
  int wid  = threadIdx.x >> 6;
  int lane = threadIdx.x & 63;
  __shared__ uint32_t woff[4];
  __shared__ uint32_t sbase;
  if (lane==0) woff[wid] = __popcll(m);
  __syncthreads();
  if (threadIdx.x==0){
    uint32_t a=0;
    #pragma unroll
    for (int i=0;i<4;i++){ uint32_t c=woff[i]; woff[i]=a; a+=c; }
    sbase = a ? atomicAdd(&meta[M_CNT(b)], a) : 0u;
  }
  __syncthreads();
  if (sel){
    uint32_t pos = sbase + woff[wid] + (uint32_t)__popcll(m & ((1ULL<<lane)-1ULL));
    if (pos < CAP){
      uint32_t idx = (uint32_t)hw*NA + (uint32_t)ch;
      cand[((size_t)b<<14) + pos] = ((uint64_t)k << 18) | (uint64_t)idx;
    }
  }
}

// ======== pass 4: bitonic sort, decomposed (identical (k,j) network) ========
__global__ __launch_bounds__(256) void bsort_local_k(uint64_t* __restrict__ buf){
  __shared__ uint64_t S[2048];
  int blk = blockIdx.x;
  int b = blk>>3, chunk = blk&7;
  uint64_t* A_ = buf + ((size_t)b<<14) + ((size_t)chunk<<11);
  int t = threadIdx.x;
  int gbase = chunk<<11;
  for (int i=t;i<2048;i+=256) S[i]=A_[i];
  __syncthreads();
  for (unsigned k=2;k<=2048u;k<<=1){
    for (unsigned j=k>>1;j>0;j>>=1){
      for (int i=t;i<2048;i+=256){
        int l = i ^ (int)j;
        if (l > i){
          bool asc = (((gbase+i) & (int)k)==0);
          uint64_t a=S[i], c=S[l];
          bool sw = asc ? (a>c) : (a<c);
          if (sw){ S[i]=c; S[l]=a; }
        }
      }
      __syncthreads();
    }
  }
  for (int i=t;i<2048;i+=256) A_[i]=S[i];
}

__global__ __launch_bounds__(256) void bsort_pass_k(uint64_t* __restrict__ buf, int k, int j){
  int p = blockIdx.x*256 + threadIdx.x;
  int b = p >> 13;
  int q = p & 8191;
  int i = ((q & ~(j-1))<<1) | (q & (j-1));
  int l = i + j;
  uint64_t* A_ = buf + ((size_t)b<<14);
  uint64_t a=A_[i], c=A_[l];
  bool asc = ((i & k)==0);
  bool sw = asc ? (a>c) : (a<c);
  if (sw){ A_[i]=c; A_[l]=a; }
}

__global__ __launch_bounds__(256) void bsort_finish_k(uint64_t* __restrict__ buf, int k){
  __shared__ uint64_t S[2048];
  int blk = blockIdx.x;
  int b = blk>>3, chunk = blk&7;
  uint64_t* A_ = buf + ((size_t)b<<14) + ((size_t)chunk<<11);
  int t = threadIdx.x;
  bool asc = (((chunk<<11) & k)==0);
  for (int i=t;i<2048;i+=256) S[i]=A_[i];
  __syncthreads();
  for (unsigned j=1024;j>0;j>>=1){
    for (int i=t;i<2048;i+=256){
      int l = i ^ (int)j;
      if (l > i){
        uint64_t a=S[i], c=S[l];
        bool sw = asc ? (a>c) : (a<c);
        if (sw){ S[i]=c; S[l]=a; }
      }
    }
    __syncthreads();
  }
  for (int i=t;i<2048;i+=256) A_[i]=S[i];
}

// -------- pass 5: decode top-12000 boxes (exact f32 ref arithmetic) --------
__global__ void extract_k(const uint64_t* __restrict__ cand2,
                          const float* __restrict__ deltas,
                          const float* __restrict__ iminfo,
                          float* __restrict__ tb){
  int g = blockIdx.x*256 + threadIdx.x;
  if (g >= NB*PRE) return;
  int b = g / PRE, j = g - b*PRE;
  uint64_t K = cand2[((size_t)b<<14) + j];
  uint32_t idx = (uint32_t)K & 0x3FFFFu;
  int ch = (int)(idx % NA);
  int hw = (int)(idx / NA);
  int w  = hw & (WF-1);
  int h  = hw >> 7;
  float sx = (float)(w*16), sy = (float)(h*16);
  float ax1 = c_ax1[ch]+sx, ay1 = c_ay1[ch]+sy, ax2 = c_ax2[ch]+sx, ay2 = c_ay2[ch]+sy;
  const float* dp = deltas + ((size_t)(b*4*NA + ch*4) << 14) + hw;
  float dx = dp[0], dy = dp[HW], dwv = dp[2*HW], dhv = dp[3*HW];
  float aw  = __fadd_rn(__fsub_rn(ax2,ax1),1.f);
  float ah  = __fadd_rn(__fsub_rn(ay2,ay1),1.f);
  float acx = __fadd_rn(ax1, __fmul_rn(0.5f,aw));
  float acy = __fadd_rn(ay1, __fmul_rn(0.5f,ah));
  float pcx = __fadd_rn(__fmul_rn(dx,aw), acx);
  float pcy = __fadd_rn(__fmul_rn(dy,ah), acy);
  float ew  = (float)exp((double)dwv);
  float eh  = (float)exp((double)dhv);
  float pw  = __fmul_rn(ew, aw);
  float ph  = __fmul_rn(eh, ah);
  float hx  = __fmul_rn(0.5f,pw), hy = __fmul_rn(0.5f,ph);
  float x1 = __fsub_rn(pcx,hx), y1 = __fsub_rn(pcy,hy);
  float x2 = __fadd_rn(pcx,hx), y2 = __fadd_rn(pcy,hy);
  float maxx = __fsub_rn(iminfo[b*3+1],1.f);
  float maxy = __fsub_rn(iminfo[b*3+0],1.f);
  x1 = fminf(fmaxf(x1,0.f),maxx); y1 = fminf(fmaxf(y1,0.f),maxy);
  x2 = fminf(fmaxf(x2,0.f),maxx); y2 = fminf(fmaxf(y2,0.f),maxy);
  float area = __fmul_rn(__fadd_rn(__fsub_rn(x2,x1),1.f), __fadd_rn(__fsub_rn(y2,y1),1.f));
  int o = b*PRE + j;
  tb[o]            = x1;
  tb[NB*PRE + o]   = y1;
  tb[2*NB*PRE + o] = x2;
  tb[3*NB*PRE + o] = y2;
  tb[4*NB*PRE + o] = area;
}

// -------- NMS phase a: chunk candidates vs already-kept boxes --------
__global__ void cross_k(const float* __restrict__ tb, const uint32_t* __restrict__ keep,
                        const uint32_t* __restrict__ meta, uint64_t* __restrict__ presup,
                        int base){
  int b  = blockIdx.y;
  int jl = blockIdx.x*256 + threadIdx.x;
  int j  = base + jl;
  bool valid = (j < PRE);
  float x1=0,y1=0,x2=0,y2=0,ar=0;
  if (valid){
    int o = b*PRE + j;
    x1=tb[o]; y1=tb[NB*PRE+o]; x2=tb[2*NB*PRE+o]; y2=tb[3*NB*PRE+o]; ar=tb[4*NB*PRE+o];
  }
  int nk = (int)meta[32+b];
  __shared__ float kx1[256],ky1[256],kx2[256],ky2[256],kar[256];
  bool supp = !valid;
  for (int k0=0; k0<nk; k0+=256){
    int kk = k0 + threadIdx.x;
    if (kk < nk){
      int kj = (int)keep[b*POST+kk];
      int o = b*PRE + kj;
      kx1[threadIdx.x]=tb[o]; ky1[threadIdx.x]=tb[NB*PRE+o];
      kx2[threadIdx.x]=tb[2*NB*PRE+o]; ky2[threadIdx.x]=tb[3*NB*PRE+o];
      kar[threadIdx.x]=tb[4*NB*PRE+o];
    }
    __syncthreads();
    int lim = min(256, nk-k0);
    if (!supp){
      for (int q=0;q<lim;q++){
        if (iou_gt(kx1[q],ky1[q],kx2[q],ky2[q],kar[q], x1,y1,x2,y2,ar)){ supp=true; break; }
      }
    }
    __syncthreads();
  }
  unsigned long long m = __ballot(supp);
  if ((threadIdx.x & 63)==0) presup[b*32 + (jl>>6)] = m;
}

// -------- NMS phase b: intra-chunk pairwise bit-matrix --------
__global__ void intra_k(const float* __restrict__ tb, uint64_t* __restrict__ Mm, int base){
  int b  = blockIdx.y;
  int il = blockIdx.x*8 + (threadIdx.x>>5);
  int jw = threadIdx.x & 31;
  __shared__ float sx1[CHUNK],sy1[CHUNK],sx2[CHUNK],sy2[CHUNK],sar[CHUNK]; // 40 KB
  for (int s = threadIdx.x; s < CHUNK; s += 256){
    int j = base + s;
    if (j < PRE){
      int o = b*PRE + j;
      sx1[s]=tb[o]; sy1[s]=tb[NB*PRE+o]; sx2[s]=tb[2*NB*PRE+o]; sy2[s]=tb[3*NB*PRE+o]; sar[s]=tb[4*NB*PRE+o];
    } else { sx1[s]=0.f; sy1[s]=0.f; sx2[s]=-10.f; sy2[s]=-10.f; sar[s]=1.f; }
  }
  __syncthreads();
  size_t mo = (((size_t)b*CHUNK) + (size_t)il)*32 + jw;
  int i = base + il;
  if (i >= PRE)          { Mm[mo] = 0; return; }
  if ((jw+1)*64 <= il)   { Mm[mo] = 0; return; }
  float x1=sx1[il], y1=sy1[il], x2=sx2[il], y2=sy2[il], ar=sar[il];
  uint64_t bits = 0;
  int jbase = jw*64;
  for (int q=0;q<64;q++){
    int jl = jbase+q;
    bool s = (base+jl < PRE) && iou_gt(x1,y1,x2,y2,ar, sx1[jl],sy1[jl],sx2[jl],sy2[jl],sar[jl]);
    bits |= ((uint64_t)s) << q;
  }
  Mm[mo] = bits;
}

// -------- NMS phase c: word-batched greedy scan, deep-MLP row-OR + tile prefetch --------
// Same algorithm as validated word-batched scan (bit-identical keep lists).
__global__ __launch_bounds__(64) void scan_k(const uint64_t* __restrict__ Mm,
                                             const uint64_t* __restrict__ presup,
                                             uint32_t* __restrict__ keep,
                                             uint32_t* __restrict__ meta,
                                             int base){
  int b = blockIdx.x;
  int l = threadIdx.x;
  uint64_t acc = (l<32) ? presup[b*32+l] : ~0ULL;
  int nk = (int)meta[32+b];
  const uint64_t* Mb = Mm + (size_t)b*CHUNK*32;
  uint64_t tile = Mb[(size_t)l*32 + 0];            // word 0 tile
  for (int w=0; w<32; w++){
    if (nk >= POST) break;
    uint64_t tile_nx = (w<31) ? Mb[(size_t)((w+1)*64+l)*32 + (w+1)] : 0ULL;  // prefetch
    uint64_t cur  = __shfl(acc, w);
    uint64_t kmask = 0;
    while (cur != ~0ULL && nk < POST){
      int p = __ffsll((unsigned long long)(~cur)) - 1;
      if (l==0) keep[b*POST+nk] = (uint32_t)(base + w*64 + p);
      nk++;
      kmask |= (1ULL<<p);
      cur |= (1ULL<<p) | (uint64_t)__shfl(tile, p);
    }
    // OR kept rows into acc, 8 loads in flight per wait
    while (kmask){
      int pp[8];
      #pragma unroll
      for (int i=0;i<8;i++){
        if (kmask){ pp[i] = __ffsll((unsigned long long)kmask)-1; kmask &= kmask-1ULL; }
        else pp[i] = -1;
      }
      uint64_t v0 = (pp[0]>=0 && l<32) ? Mb[(size_t)(w*64+pp[0])*32 + l] : 0ULL;
      uint64_t v1 = (pp[1]>=0 && l<32) ? Mb[(size_t)(w*64+pp[1])*32 + l] : 0ULL;
      uint64_t v2 = (pp[2]>=0 && l<32) ? Mb[(size_t)(w*64+pp[2])*32 + l] : 0ULL;
      uint64_t v3 = (pp[3]>=0 && l<32) ? Mb[(size_t)(w*64+pp[3])*32 + l] : 0ULL;
      uint64_t v4 = (pp[4]>=0 && l<32) ? Mb[(size_t)(w*64+pp[4])*32 + l] : 0ULL;
      uint64_t v5 = (pp[5]>=0 && l<32) ? Mb[(size_t)(w*64+pp[5])*32 + l] : 0ULL;
      uint64_t v6 = (pp[6]>=0 && l<32) ? Mb[(size_t)(w*64+pp[6])*32 + l] : 0ULL;
      uint64_t v7 = (pp[7]>=0 && l<32) ? Mb[(size_t)(w*64+pp[7])*32 + l] : 0ULL;
      acc |= ((v0|v1)|(v2|v3)) | ((v4|v5)|(v6|v7));
    }
    tile = tile_nx;
  }
  if (l==0) meta[32+b] = (uint32_t)nk;
}

// -------- output (f32) --------
__global__ void finalize_k(const float* __restrict__ tb, const uint32_t* __restrict__ keep,
                           const uint32_t* __restrict__ meta, float* __restrict__ out){
  int g = blockIdx.x*256 + threadIdx.x;
  if (g >= NB*POST) return;
  int b = g / POST, i = g - b*POST;
  float x1=0.f,y1=0.f,x2=0.f,y2=0.f;
  if (i < (int)meta[32+b]){
    int j = (int)keep[b*POST+i];
    int o = b*PRE + j;
    x1=tb[o]; y1=tb[NB*PRE+o]; x2=tb[2*NB*PRE+o]; y2=tb[3*NB*PRE+o];
  }
  float* op = out + (size_t)g*5;
  op[0]=(float)b; op[1]=x1; op[2]=y1; op[3]=x2; op[4]=y2;
}

extern "C" void kernel_launch(void* const* d_in, const int* in_sizes, int n_in,
                              void* d_out, int out_size, void* d_ws, size_t ws_size,
                              hipStream_t stream){
  (void)in_sizes; (void)n_in; (void)out_size; (void)ws_size;
  const float* scores = (const float*)d_in[0];
  const float* deltas = (const float*)d_in[1];
  const float* iminfo = (const float*)d_in[2];
  float* out = (float*)d_out;
  char* ws = (char*)d_ws;

  uint32_t* hist  = (uint32_t*)(ws + OFF_HIST);
  uint32_t* meta  = (uint32_t*)(ws + OFF_META);
  uint64_t* cand  = (uint64_t*)(ws + OFF_CAND);
  float*    tb    = (float*)   (ws + OFF_TB);
  uint32_t* keep  = (uint32_t*)(ws + OFF_KEEP);
  uint64_t* pres  = (uint64_t*)(ws + OFF_PRES);
  uint64_t* Mm    = (uint64_t*)(ws + OFF_M);

  hipMemsetAsync(ws + OFF_HIST, 0, SZ_HIST + SZ_META, stream);
  hipMemsetAsync(ws + OFF_CAND, 0xFF, SZ_CAND, stream);

  prep_k    <<<(NB*NTOT+255)/256, 256, 0, stream>>>(scores, hist);
  scanhist_k<<<NB, 1024, 0, stream>>>(hist, meta);
  gather_k  <<<NB*NTOT/256, 256, 0, stream>>>(scores, meta, cand);

  bsort_local_k<<<NB*8, 256, 0, stream>>>(cand);
  for (int k=4096; k<=16384; k<<=1){
    for (int j=k>>1; j>=2048; j>>=1)
      bsort_pass_k<<<NB*8192/256, 256, 0, stream>>>(cand, k, j);
    bsort_finish_k<<<NB*8, 256, 0, stream>>>(cand, k);
  }

  extract_k <<<(NB*PRE+255)/256, 256, 0, stream>>>(cand, deltas, iminfo, tb);
  for (int ph=0; ph<NPH; ph++){
    int base = ph*CHUNK;
    cross_k<<<dim3(CHUNK/256, NB), 256, 0, stream>>>(tb, keep, meta, pres, base);
    intra_k<<<dim3(CHUNK/8,   NB), 256, 0, stream>>>(tb, Mm, base);
    scan_k <<<NB, 64, 0, stream>>>(Mm, pres, keep, meta, base);
  }
  finalize_k<<<(NB*POST+255)/256, 256, 0, stream>>>(tb, keep, meta, out);
}

// Round 12
// 3982.375 us; speedup vs baseline: 7.9298x; 1.0870x over previous
//
#include <hip/hip_runtime.h>
#include <stdint.h>
#include <math.h>

#define NB   16
#define HF   128
#define WF   128
#define NA   9
#define HW   (HF*WF)          // 16384
#define NTOT (HW*NA)          // 147456
#define PRE  12000
#define POST 2000
#define CAP  16384
#define CHUNK 2048
#define NPH  6

// ws layout (bytes)
#define OFF_HIST  0u
#define SZ_HIST   (NB*65536u*4u)            // 4,194,304
#define OFF_META  (OFF_HIST + SZ_HIST)
#define SZ_META   4096u   // words: [0..15] cutoff | [32..47] nk | [256+b*16] gather count (64B-padded)
#define OFF_CAND  (OFF_META + SZ_META)
#define SZ_CAND   (NB*CAP*8u)               // 2,097,152
#define OFF_TB    (OFF_CAND + SZ_CAND)
#define SZ_TB     (5u*NB*PRE*4u)            // 3,840,000
#define OFF_KEEP  (OFF_TB + SZ_TB)
#define SZ_KEEP   (NB*POST*4u)              // 128,000
#define OFF_PRES  (OFF_KEEP + SZ_KEEP)
#define SZ_PRES   (NB*32u*8u)               // 4,096
#define OFF_M     (OFF_PRES + SZ_PRES)
#define SZ_M      ((size_t)NB*CHUNK*32u*8u) // 8,388,608

#define M_CNT(b)  (256 + (b)*16)

// base anchors = classic py-faster-rcnn table minus 1 (base [0,0,15,15]); a8.y2=359.
__constant__ float c_ax1[NA] = {-84.f,-176.f,-360.f,-56.f,-120.f,-248.f,-36.f,-80.f,-168.f};
__constant__ float c_ay1[NA] = {-40.f,-88.f,-184.f,-56.f,-120.f,-248.f,-80.f,-168.f,-344.f};
__constant__ float c_ax2[NA] = { 99.f, 191.f, 375.f, 71.f, 135.f, 263.f, 51.f, 95.f, 183.f};
__constant__ float c_ay2[NA] = { 55.f, 103.f, 199.f, 71.f, 135.f, 263.f, 95.f, 183.f, 359.f};

__device__ __forceinline__ uint32_t score_key(float f){
  uint32_t b = __float_as_uint(f);
  uint32_t u = (b & 0x80000000u) ? ~b : (b | 0x80000000u);
  return ~u;   // ascending key = descending score; idx in low bits -> stable ties
}

__device__ __forceinline__ bool iou_gt(float ax1,float ay1,float ax2,float ay2,float aa,
                                       float bx1,float by1,float bx2,float by2,float ba){
  float xx1 = fmaxf(ax1,bx1);
  float yy1 = fmaxf(ay1,by1);
  float xx2 = fminf(ax2,bx2);
  float yy2 = fminf(ay2,by2);
  float w = fmaxf(__fadd_rn(__fsub_rn(xx2,xx1),1.0f), 0.0f);
  float h = fmaxf(__fadd_rn(__fsub_rn(yy2,yy1),1.0f), 0.0f);
  float inter = __fmul_rn(w,h);
  float denom = __fsub_rn(__fadd_rn(aa,ba), inter);
  float iou   = __fdiv_rn(inter, denom);
  return iou > 0.7f;
}

// -------- pass 1: histogram of score keys (top 16 bits) --------
__global__ void prep_k(const float* __restrict__ scores, uint32_t* __restrict__ hist){
  int g = blockIdx.x*256 + threadIdx.x;
  if (g >= NB*NTOT) return;
  int hw = g & (HW-1);
  int t  = g >> 14;
  int ch = t % NA;
  int b  = t / NA;
  float s = scores[((size_t)(b*2*NA + NA + ch) << 14) + hw];
  uint32_t k = score_key(s);
  atomicAdd(&hist[((uint32_t)b<<16) + (k>>16)], 1u);
}

// -------- pass 2: find cutoff bucket per batch --------
__global__ __launch_bounds__(1024) void scanhist_k(const uint32_t* __restrict__ hist,
                                                   uint32_t* __restrict__ meta){
  int b = blockIdx.x, t = threadIdx.x;
  const uint32_t* hh = hist + ((uint32_t)b<<16);
  int base = t<<6;
  uint32_t s=0;
  for (int i=0;i<64;i++) s += hh[base+i];
  __shared__ uint32_t part[1024];
  part[t]=s; __syncthreads();
  for (int off=1; off<1024; off<<=1){
    uint32_t v = (t>=off)? part[t-off] : 0u;
    __syncthreads();
    part[t] += v;
    __syncthreads();
  }
  uint32_t incl = part[t], excl = incl - s;
  if (excl < PRE && incl >= PRE){
    uint32_t run = excl;
    for (int i=0;i<64;i++){
      run += hh[base+i];
      if (run >= PRE){ meta[b] = (uint32_t)(base+i); break; }
    }
  }
}

// -------- pass 3: gather (block-aggregated atomics) --------
__global__ __launch_bounds__(256) void gather_k(const float* __restrict__ scores,
                                                uint32_t* __restrict__ meta,
                                                uint64_t* __restrict__ cand){
  int g = blockIdx.x*256 + threadIdx.x;
  int hw = g & (HW-1);
  int t  = g >> 14;
  int ch = t % NA;
  int b  = t / NA;
  float s = scores[((size_t)(b*2*NA + NA + ch) << 14) + hw];
  uint32_t k = score_key(s);
  bool sel = (k>>16) <= meta[b];
  unsigned long long m = __ballot(sel);
  int wid  = threadIdx.x >> 6;
  int lane = threadIdx.x & 63;
  __shared__ uint32_t woff[4];
  __shared__ uint32_t sbase;
  if (lane==0) woff[wid] = __popcll(m);
  __syncthreads();
  if (threadIdx.x==0){
    uint32_t a=0;
    #pragma unroll
    for (int i=0;i<4;i++){ uint32_t c=woff[i]; woff[i]=a; a+=c; }
    sbase = a ? atomicAdd(&meta[M_CNT(b)], a) : 0u;
  }
  __syncthreads();
  if (sel){
    uint32_t pos = sbase + woff[wid] + (uint32_t)__popcll(m & ((1ULL<<lane)-1ULL));
    if (pos < CAP){
      uint32_t idx = (uint32_t)hw*NA + (uint32_t)ch;
      cand[((size_t)b<<14) + pos] = ((uint64_t)k << 18) | (uint64_t)idx;
    }
  }
}

// ======== pass 4: bitonic sort, decomposed (identical (k,j) network) ========
__global__ __launch_bounds__(256) void bsort_local_k(uint64_t* __restrict__ buf){
  __shared__ uint64_t S[2048];
  int blk = blockIdx.x;
  int b = blk>>3, chunk = blk&7;
  uint64_t* A_ = buf + ((size_t)b<<14) + ((size_t)chunk<<11);
  int t = threadIdx.x;
  int gbase = chunk<<11;
  for (int i=t;i<2048;i+=256) S[i]=A_[i];
  __syncthreads();
  for (unsigned k=2;k<=2048u;k<<=1){
    for (unsigned j=k>>1;j>0;j>>=1){
      for (int i=t;i<2048;i+=256){
        int l = i ^ (int)j;
        if (l > i){
          bool asc = (((gbase+i) & (int)k)==0);
          uint64_t a=S[i], c=S[l];
          bool sw = asc ? (a>c) : (a<c);
          if (sw){ S[i]=c; S[l]=a; }
        }
      }
      __syncthreads();
    }
  }
  for (int i=t;i<2048;i+=256) A_[i]=S[i];
}

__global__ __launch_bounds__(256) void bsort_pass_k(uint64_t* __restrict__ buf, int k, int j){
  int p = blockIdx.x*256 + threadIdx.x;
  int b = p >> 13;
  int q = p & 8191;
  int i = ((q & ~(j-1))<<1) | (q & (j-1));
  int l = i + j;
  uint64_t* A_ = buf + ((size_t)b<<14);
  uint64_t a=A_[i], c=A_[l];
  bool asc = ((i & k)==0);
  bool sw = asc ? (a>c) : (a<c);
  if (sw){ A_[i]=c; A_[l]=a; }
}

__global__ __launch_bounds__(256) void bsort_finish_k(uint64_t* __restrict__ buf, int k){
  __shared__ uint64_t S[2048];
  int blk = blockIdx.x;
  int b = blk>>3, chunk = blk&7;
  uint64_t* A_ = buf + ((size_t)b<<14) + ((size_t)chunk<<11);
  int t = threadIdx.x;
  bool asc = (((chunk<<11) & k)==0);
  for (int i=t;i<2048;i+=256) S[i]=A_[i];
  __syncthreads();
  for (unsigned j=1024;j>0;j>>=1){
    for (int i=t;i<2048;i+=256){
      int l = i ^ (int)j;
      if (l > i){
        uint64_t a=S[i], c=S[l];
        bool sw = asc ? (a>c) : (a<c);
        if (sw){ S[i]=c; S[l]=a; }
      }
    }
    __syncthreads();
  }
  for (int i=t;i<2048;i+=256) A_[i]=S[i];
}

// -------- pass 5: decode top-12000 boxes (exact f32 ref arithmetic) --------
__global__ void extract_k(const uint64_t* __restrict__ cand2,
                          const float* __restrict__ deltas,
                          const float* __restrict__ iminfo,
                          float* __restrict__ tb){
  int g = blockIdx.x*256 + threadIdx.x;
  if (g >= NB*PRE) return;
  int b = g / PRE, j = g - b*PRE;
  uint64_t K = cand2[((size_t)b<<14) + j];
  uint32_t idx = (uint32_t)K & 0x3FFFFu;
  int ch = (int)(idx % NA);
  int hw = (int)(idx / NA);
  int w  = hw & (WF-1);
  int h  = hw >> 7;
  float sx = (float)(w*16), sy = (float)(h*16);
  float ax1 = c_ax1[ch]+sx, ay1 = c_ay1[ch]+sy, ax2 = c_ax2[ch]+sx, ay2 = c_ay2[ch]+sy;
  const float* dp = deltas + ((size_t)(b*4*NA + ch*4) << 14) + hw;
  float dx = dp[0], dy = dp[HW], dwv = dp[2*HW], dhv = dp[3*HW];
  float aw  = __fadd_rn(__fsub_rn(ax2,ax1),1.f);
  float ah  = __fadd_rn(__fsub_rn(ay2,ay1),1.f);
  float acx = __fadd_rn(ax1, __fmul_rn(0.5f,aw));
  float acy = __fadd_rn(ay1, __fmul_rn(0.5f,ah));
  float pcx = __fadd_rn(__fmul_rn(dx,aw), acx);
  float pcy = __fadd_rn(__fmul_rn(dy,ah), acy);
  float ew  = (float)exp((double)dwv);
  float eh  = (float)exp((double)dhv);
  float pw  = __fmul_rn(ew, aw);
  float ph  = __fmul_rn(eh, ah);
  float hx  = __fmul_rn(0.5f,pw), hy = __fmul_rn(0.5f,ph);
  float x1 = __fsub_rn(pcx,hx), y1 = __fsub_rn(pcy,hy);
  float x2 = __fadd_rn(pcx,hx), y2 = __fadd_rn(pcy,hy);
  float maxx = __fsub_rn(iminfo[b*3+1],1.f);
  float maxy = __fsub_rn(iminfo[b*3+0],1.f);
  x1 = fminf(fmaxf(x1,0.f),maxx); y1 = fminf(fmaxf(y1,0.f),maxy);
  x2 = fminf(fmaxf(x2,0.f),maxx); y2 = fminf(fmaxf(y2,0.f),maxy);
  float area = __fmul_rn(__fadd_rn(__fsub_rn(x2,x1),1.f), __fadd_rn(__fsub_rn(y2,y1),1.f));
  int o = b*PRE + j;
  tb[o]            = x1;
  tb[NB*PRE + o]   = y1;
  tb[2*NB*PRE + o] = x2;
  tb[3*NB*PRE + o] = y2;
  tb[4*NB*PRE + o] = area;
}

// -------- NMS phase a: chunk candidates vs already-kept boxes --------
__global__ void cross_k(const float* __restrict__ tb, const uint32_t* __restrict__ keep,
                        const uint32_t* __restrict__ meta, uint64_t* __restrict__ presup,
                        int base){
  int b  = blockIdx.y;
  int jl = blockIdx.x*256 + threadIdx.x;
  int j  = base + jl;
  bool valid = (j < PRE);
  float x1=0,y1=0,x2=0,y2=0,ar=0;
  if (valid){
    int o = b*PRE + j;
    x1=tb[o]; y1=tb[NB*PRE+o]; x2=tb[2*NB*PRE+o]; y2=tb[3*NB*PRE+o]; ar=tb[4*NB*PRE+o];
  }
  int nk = (int)meta[32+b];
  __shared__ float kx1[256],ky1[256],kx2[256],ky2[256],kar[256];
  bool supp = !valid;
  for (int k0=0; k0<nk; k0+=256){
    int kk = k0 + threadIdx.x;
    if (kk < nk){
      int kj = (int)keep[b*POST+kk];
      int o = b*PRE + kj;
      kx1[threadIdx.x]=tb[o]; ky1[threadIdx.x]=tb[NB*PRE+o];
      kx2[threadIdx.x]=tb[2*NB*PRE+o]; ky2[threadIdx.x]=tb[3*NB*PRE+o];
      kar[threadIdx.x]=tb[4*NB*PRE+o];
    }
    __syncthreads();
    int lim = min(256, nk-k0);
    if (!supp){
      for (int q=0;q<lim;q++){
        if (iou_gt(kx1[q],ky1[q],kx2[q],ky2[q],kar[q], x1,y1,x2,y2,ar)){ supp=true; break; }
      }
    }
    __syncthreads();
  }
  unsigned long long m = __ballot(supp);
  if ((threadIdx.x & 63)==0) presup[b*32 + (jl>>6)] = m;
}

// -------- NMS phase b: intra-chunk bit-matrix, row-per-thread (broadcast LDS reads) --------
// Bit-identical M to previous version: straddling words compute real IoUs (symmetric),
// fully-below-diagonal words are zero, i>=PRE rows are zero.
__global__ __launch_bounds__(256) void intra_k(const float* __restrict__ tb,
                                               uint64_t* __restrict__ Mm, int base){
  int b  = blockIdx.y;
  int il = blockIdx.x*256 + threadIdx.x;
  __shared__ float4 sbx[CHUNK];       // (x1,y1,x2,y2)
  __shared__ float  sar[CHUNK];       // area           -- 40 KB total
  for (int s = threadIdx.x; s < CHUNK; s += 256){
    int j = base + s;
    if (j < PRE){
      int o = b*PRE + j;
      sbx[s] = make_float4(tb[o], tb[NB*PRE+o], tb[2*NB*PRE+o], tb[3*NB*PRE+o]);
      sar[s] = tb[4*NB*PRE+o];
    } else { sbx[s] = make_float4(0.f,0.f,-10.f,-10.f); sar[s] = 1.f; }
  }
  __syncthreads();
  uint64_t* Mr = Mm + (((size_t)b*CHUNK) + (size_t)il)*32;
  int i = base + il;
  if (i >= PRE){
    for (int w=0; w<32; w++) Mr[w] = 0;
    return;
  }
  float4 bb = sbx[il];
  float  ar = sar[il];
  int w0 = il >> 6;                    // words fully below diagonal are zero
  for (int w=0; w<w0; w++) Mr[w] = 0;
  int jmax = PRE - base;               // cols >= jmax are padding (no suppress)
  for (int w=w0; w<32; w++){
    uint64_t bits = 0;
    int jb = w<<6;
    #pragma unroll 8
    for (int q=0; q<64; q++){
      int jl = jb + q;
      float4 cb = sbx[jl];
      bool s = (jl < jmax) && iou_gt(bb.x,bb.y,bb.z,bb.w,ar, cb.x,cb.y,cb.z,cb.w,sar[jl]);
      bits |= ((uint64_t)s) << q;
    }
    Mr[w] = bits;
  }
}

// -------- NMS phase c: word-batched greedy scan, deep-MLP row-OR + tile prefetch --------
__global__ __launch_bounds__(64) void scan_k(const uint64_t* __restrict__ Mm,
                                             const uint64_t* __restrict__ presup,
                                             uint32_t* __restrict__ keep,
                                             uint32_t* __restrict__ meta,
                                             int base){
  int b = blockIdx.x;
  int l = threadIdx.x;
  uint64_t acc = (l<32) ? presup[b*32+l] : ~0ULL;
  int nk = (int)meta[32+b];
  const uint64_t* Mb = Mm + (size_t)b*CHUNK*32;
  uint64_t tile = Mb[(size_t)l*32 + 0];
  for (int w=0; w<32; w++){
    if (nk >= POST) break;
    uint64_t tile_nx = (w<31) ? Mb[(size_t)((w+1)*64+l)*32 + (w+1)] : 0ULL;
    uint64_t cur  = __shfl(acc, w);
    uint64_t kmask = 0;
    while (cur != ~0ULL && nk < POST){
      int p = __ffsll((unsigned long long)(~cur)) - 1;
      if (l==0) keep[b*POST+nk] = (uint32_t)(base + w*64 + p);
      nk++;
      kmask |= (1ULL<<p);
      cur |= (1ULL<<p) | (uint64_t)__shfl(tile, p);
    }
    while (kmask){
      int pp[8];
      #pragma unroll
      for (int i=0;i<8;i++){
        if (kmask){ pp[i] = __ffsll((unsigned long long)kmask)-1; kmask &= kmask-1ULL; }
        else pp[i] = -1;
      }
      uint64_t v0 = (pp[0]>=0 && l<32) ? Mb[(size_t)(w*64+pp[0])*32 + l] : 0ULL;
      uint64_t v1 = (pp[1]>=0 && l<32) ? Mb[(size_t)(w*64+pp[1])*32 + l] : 0ULL;
      uint64_t v2 = (pp[2]>=0 && l<32) ? Mb[(size_t)(w*64+pp[2])*32 + l] : 0ULL;
      uint64_t v3 = (pp[3]>=0 && l<32) ? Mb[(size_t)(w*64+pp[3])*32 + l] : 0ULL;
      uint64_t v4 = (pp[4]>=0 && l<32) ? Mb[(size_t)(w*64+pp[4])*32 + l] : 0ULL;
      uint64_t v5 = (pp[5]>=0 && l<32) ? Mb[(size_t)(w*64+pp[5])*32 + l] : 0ULL;
      uint64_t v6 = (pp[6]>=0 && l<32) ? Mb[(size_t)(w*64+pp[6])*32 + l] : 0ULL;
      uint64_t v7 = (pp[7]>=0 && l<32) ? Mb[(size_t)(w*64+pp[7])*32 + l] : 0ULL;
      acc |= ((v0|v1)|(v2|v3)) | ((v4|v5)|(v6|v7));
    }
    tile = tile_nx;
  }
  if (l==0) meta[32+b] = (uint32_t)nk;
}

// -------- output (f32) --------
__global__ void finalize_k(const float* __restrict__ tb, const uint32_t* __restrict__ keep,
                           const uint32_t* __restrict__ meta, float* __restrict__ out){
  int g = blockIdx.x*256 + threadIdx.x;
  if (g >= NB*POST) return;
  int b = g / POST, i = g - b*POST;
  float x1=0.f,y1=0.f,x2=0.f,y2=0.f;
  if (i < (int)meta[32+b]){
    int j = (int)keep[b*POST+i];
    int o = b*PRE + j;
    x1=tb[o]; y1=tb[NB*PRE+o]; x2=tb[2*NB*PRE+o]; y2=tb[3*NB*PRE+o];
  }
  float* op = out + (size_t)g*5;
  op[0]=(float)b; op[1]=x1; op[2]=y1; op[3]=x2; op[4]=y2;
}

extern "C" void kernel_launch(void* const* d_in, const int* in_sizes, int n_in,
                              void* d_out, int out_size, void* d_ws, size_t ws_size,
                              hipStream_t stream){
  (void)in_sizes; (void)n_in; (void)out_size; (void)ws_size;
  const float* scores = (const float*)d_in[0];
  const float* deltas = (const float*)d_in[1];
  const float* iminfo = (const float*)d_in[2];
  float* out = (float*)d_out;
  char* ws = (char*)d_ws;

  uint32_t* hist  = (uint32_t*)(ws + OFF_HIST);
  uint32_t* meta  = (uint32_t*)(ws + OFF_META);
  uint64_t* cand  = (uint64_t*)(ws + OFF_CAND);
  float*    tb    = (float*)   (ws + OFF_TB);
  uint32_t* keep  = (uint32_t*)(ws + OFF_KEEP);
  uint64_t* pres  = (uint64_t*)(ws + OFF_PRES);
  uint64_t* Mm    = (uint64_t*)(ws + OFF_M);

  hipMemsetAsync(ws + OFF_HIST, 0, SZ_HIST + SZ_META, stream);
  hipMemsetAsync(ws + OFF_CAND, 0xFF, SZ_CAND, stream);

  prep_k    <<<(NB*NTOT+255)/256, 256, 0, stream>>>(scores, hist);
  scanhist_k<<<NB, 1024, 0, stream>>>(hist, meta);
  gather_k  <<<NB*NTOT/256, 256, 0, stream>>>(scores, meta, cand);

  bsort_local_k<<<NB*8, 256, 0, stream>>>(cand);
  for (int k=4096; k<=16384; k<<=1){
    for (int j=k>>1; j>=2048; j>>=1)
      bsort_pass_k<<<NB*8192/256, 256, 0, stream>>>(cand, k, j);
    bsort_finish_k<<<NB*8, 256, 0, stream>>>(cand, k);
  }

  extract_k <<<(NB*PRE+255)/256, 256, 0, stream>>>(cand, deltas, iminfo, tb);
  for (int ph=0; ph<NPH; ph++){
    int base = ph*CHUNK;
    cross_k<<<dim3(CHUNK/256, NB), 256, 0, stream>>>(tb, keep, meta, pres, base);
    intra_k<<<dim3(CHUNK/256, NB), 256, 0, stream>>>(tb, Mm, base);
    scan_k <<<NB, 64, 0, stream>>>(Mm, pres, keep, meta, base);
  }
  finalize_k<<<(NB*POST+255)/256, 256, 0, stream>>>(tb, keep, meta, out);
}